// Round 13
// baseline (1603.421 us; speedup 1.0000x reference)
//
#include <hip/hip_runtime.h>
#include <hip/hip_bf16.h>
#include <stdint.h>

// DbrxExpertGLU: down = (silu(x@w1^T) * (x@v1^T)) @ w2
// T=4096, H=4096, F=14336. fp32 in/out; bf16 MFMA compute.
// R13 = R12 with both 256-GEMMs on v_mfma_f32_32x32x16_bf16 (2382 vs 2075 TF
// ceiling, -17% matrix-pipe cycles; LDS volume unchanged). C/D map per m74/m101:
// col=lane&31, row=(reg&3)+8*(reg>>2)+4*(lane>>5).
#define TOKENS 4096
#define HIDDEN 4096
#define FFN    14336

typedef __attribute__((ext_vector_type(8))) short bf16x8;
typedef __attribute__((ext_vector_type(4))) float f32x4;
typedef __attribute__((ext_vector_type(16))) float f32x16;
typedef __attribute__((ext_vector_type(8))) unsigned short u16x8;

typedef __attribute__((address_space(3))) void lds_void_t;
typedef const __attribute__((address_space(1))) void gbl_void_t;

static __device__ __forceinline__ unsigned short f2b(float f) {
  union { float f; unsigned int u; } v; v.f = f;
  unsigned int u = v.u;
  return (unsigned short)((u + 0x7FFFu + ((u >> 16) & 1u)) >> 16);  // RNE
}

// ---------------- fp32 -> bf16 convert ----------------
__global__ void cvt_kernel(const float* __restrict__ in, unsigned short* __restrict__ out, long n) {
  long idx = (long)blockIdx.x * blockDim.x + threadIdx.x;
  long stride = (long)gridDim.x * blockDim.x;
  for (long i = idx * 4; i < n; i += stride * 4) {
    const float4 v = *reinterpret_cast<const float4*>(in + i);
    ushort4 o;
    o.x = f2b(v.x); o.y = f2b(v.y); o.z = f2b(v.z); o.w = f2b(v.w);
    *reinterpret_cast<ushort4*>(out + i) = o;
  }
}

// ------- w2 [F][H] fp32 -> w2t [H][F] bf16 -------
__global__ void transpose_cvt_kernel(const float* __restrict__ in, unsigned short* __restrict__ out) {
  __shared__ float tile[64][65];
  const int f0 = blockIdx.x * 64;
  const int h0 = blockIdx.y * 64;
  const int t = threadIdx.x;
  const int rcol = (t & 15) * 4;
  const int rrow = t >> 4;
#pragma unroll
  for (int it = 0; it < 4; ++it) {
    int r = rrow + it * 16;
    const float4 v = *reinterpret_cast<const float4*>(in + (long)(f0 + r) * HIDDEN + h0 + rcol);
    tile[r][rcol] = v.x; tile[r][rcol + 1] = v.y; tile[r][rcol + 2] = v.z; tile[r][rcol + 3] = v.w;
  }
  __syncthreads();
  const int wrow = t >> 2;
  const int wc = (t & 3) * 16;
  u16x8 lo, hi;
#pragma unroll
  for (int j = 0; j < 8; ++j) lo[j] = f2b(tile[wc + j][wrow]);
#pragma unroll
  for (int j = 0; j < 8; ++j) hi[j] = f2b(tile[wc + 8 + j][wrow]);
  u16x8* dst = reinterpret_cast<u16x8*>(out + (long)(h0 + wrow) * FFN + f0 + wc);
  dst[0] = lo; dst[1] = hi;
}

#define MFMA32(a, b, c) __builtin_amdgcn_mfma_f32_32x32x16_bf16((a), (b), (c), 0, 0, 0)
#define MFMA16(a, b, c) __builtin_amdgcn_mfma_f32_16x16x32_bf16((a), (b), (c), 0, 0, 0)
#define SBAR()  __builtin_amdgcn_s_barrier()

static __device__ __forceinline__ int xcd_chunk(int bid, int nwg) {
  return (bid & 7) * (nwg >> 3) + (bid >> 3);
}

// ============ persistent fused gate/up: grid 256, 7 F-tiles/block, 32x32 MFMA ============
// LDS per buf (64KB): A[256][64] @0 | W[128][64] @32K | V[128][64] @48K. x2 dbuf.
__global__ __launch_bounds__(512, 2)
void gateup256p_kernel(const unsigned short* __restrict__ X,
                       const unsigned short* __restrict__ W1,
                       const unsigned short* __restrict__ V1,
                       unsigned short* __restrict__ Inter) {
  __shared__ unsigned short sh[65536];  // 128 KB
  const int tid = threadIdx.x, lane = tid & 63, wid = tid >> 6;
  const int wm = wid >> 2, wn = wid & 3;
  const int p = blockIdx.x;           // 0..255, one block per CU
  const int bm = p & 15;              // T-tile (fixed per block)
  const int bnl = p >> 4;             // bn lane 0..15
  const int sr = tid >> 3;
  const int scb = (((tid & 7) ^ (sr & 7)) << 4);
  const int l31 = lane & 31;
  const int kb16 = (lane >> 5) * 16;  // 16B half within a kstep
  const int swz = (lane & 7) << 4;    // row&7 == lane&7 for row = *+l31

  const unsigned short* Ap = X + (long)(bm * 256) * HIDDEN;

  auto LDA4 = [&](bf16x8* a, int buf, int kb) {  // 4 row-tiles, one kstep (kb bytes)
    const char* base = (const char*)sh + buf * 65536 + (wm * 128 + l31) * 128 + ((kb + kb16) ^ swz);
#pragma unroll
    for (int rt = 0; rt < 4; ++rt) a[rt] = *(const bf16x8*)(base + rt * 32 * 128);
  };
  auto LDW1 = [&](bf16x8& w, int buf, int kb) {
    const char* base = (const char*)sh + buf * 65536 + 32768 + (wn * 32 + l31) * 128 + ((kb + kb16) ^ swz);
    w = *(const bf16x8*)(base);
  };
  auto LDV1 = [&](bf16x8& v, int buf, int kb) {
    const char* base = (const char*)sh + buf * 65536 + 49152 + (wn * 32 + l31) * 128 + ((kb + kb16) ^ swz);
    v = *(const bf16x8*)(base);
  };

  for (int j = 0; j < 7; ++j) {
    const int bn = j * 16 + bnl;      // 16 bm-blocks share panel bn concurrently
    const unsigned short* Wp = W1 + (long)(bn * 128) * HIDDEN;
    const unsigned short* Vp = V1 + (long)(bn * 128) * HIDDEN;

    auto STA = [&](int u, int buf, int t) {
      const unsigned short* src = Ap + (long)(u * 64 + sr) * HIDDEN + t * 64 + (scb >> 1);
      unsigned short* dst = sh + buf * 32768 + u * 4096 + tid * 8;
      __builtin_amdgcn_global_load_lds((gbl_void_t*)src, (lds_void_t*)dst, 16, 0, 0);
    };
    auto STW = [&](int u, int buf, int t) {
      const unsigned short* src = Wp + (long)(u * 64 + sr) * HIDDEN + t * 64 + (scb >> 1);
      unsigned short* dst = sh + buf * 32768 + 16384 + u * 4096 + tid * 8;
      __builtin_amdgcn_global_load_lds((gbl_void_t*)src, (lds_void_t*)dst, 16, 0, 0);
    };
    auto STV = [&](int u, int buf, int t) {
      const unsigned short* src = Vp + (long)(u * 64 + sr) * HIDDEN + t * 64 + (scb >> 1);
      unsigned short* dst = sh + buf * 32768 + 24576 + u * 4096 + tid * 8;
      __builtin_amdgcn_global_load_lds((gbl_void_t*)src, (lds_void_t*)dst, 16, 0, 0);
    };

    f32x16 accg[4] = {};
    f32x16 accu[4] = {};

    STA(0, 0, 0); STA(1, 0, 0); STA(2, 0, 0); STA(3, 0, 0);
    STW(0, 0, 0); STW(1, 0, 0); STV(0, 0, 0); STV(1, 0, 0);

    bf16x8 a0[4], a1[4], w0, w1, v0, v1;
    const int NT = HIDDEN / 64;  // 64
    for (int t = 0; t < NT; ++t) {
      const int cur = t & 1, nxt = cur ^ 1;
      const bool pre = (t + 1 < NT);
      // P0: prefetch W+V(t+1); gate vmcnt(4); gate MFMA ks0+ks1
      if (pre) { STW(0, nxt, t + 1); STW(1, nxt, t + 1);
                 STV(0, nxt, t + 1); STV(1, nxt, t + 1);
                 asm volatile("s_waitcnt vmcnt(4)" ::: "memory"); }
      else     { asm volatile("s_waitcnt vmcnt(0)" ::: "memory"); }
      SBAR();
      LDA4(a0, cur, 0); LDA4(a1, cur, 32); LDW1(w0, cur, 0); LDW1(w1, cur, 32);
      __builtin_amdgcn_s_setprio(1);
#pragma unroll
      for (int rt = 0; rt < 4; ++rt) {
        accg[rt] = MFMA32(a0[rt], w0, accg[rt]);
        accg[rt] = MFMA32(a1[rt], w1, accg[rt]);
      }
      __builtin_amdgcn_s_setprio(0);
      SBAR();
      // P1: prefetch A(t+1); up MFMA ks0+ks1 (reuse a0,a1)
      if (pre) { STA(0, nxt, t + 1); STA(1, nxt, t + 1);
                 STA(2, nxt, t + 1); STA(3, nxt, t + 1); }
      LDV1(v0, cur, 0); LDV1(v1, cur, 32);
      __builtin_amdgcn_s_setprio(1);
#pragma unroll
      for (int rt = 0; rt < 4; ++rt) {
        accu[rt] = MFMA32(a0[rt], v0, accu[rt]);
        accu[rt] = MFMA32(a1[rt], v1, accu[rt]);
      }
      __builtin_amdgcn_s_setprio(0);
      SBAR();
      // P2: gate MFMA ks2+ks3
      LDA4(a0, cur, 64); LDA4(a1, cur, 96); LDW1(w0, cur, 64); LDW1(w1, cur, 96);
      __builtin_amdgcn_s_setprio(1);
#pragma unroll
      for (int rt = 0; rt < 4; ++rt) {
        accg[rt] = MFMA32(a0[rt], w0, accg[rt]);
        accg[rt] = MFMA32(a1[rt], w1, accg[rt]);
      }
      __builtin_amdgcn_s_setprio(0);
      SBAR();
      // P3: up MFMA ks2+ks3
      LDV1(v0, cur, 64); LDV1(v1, cur, 96);
      __builtin_amdgcn_s_setprio(1);
#pragma unroll
      for (int rt = 0; rt < 4; ++rt) {
        accu[rt] = MFMA32(a0[rt], v0, accu[rt]);
        accu[rt] = MFMA32(a1[rt], v1, accu[rt]);
      }
      __builtin_amdgcn_s_setprio(0);
      SBAR();
    }
    // epilogue: silu(g)*u -> bf16. C/D 32x32 map: col=lane&31, row=(r&3)+8*(r>>2)+4*(lane>>5)
    const int rbase = 4 * (lane >> 5);
    const int col = bn * 128 + wn * 32 + l31;
#pragma unroll
    for (int rt = 0; rt < 4; ++rt)
#pragma unroll
      for (int r = 0; r < 16; ++r) {
        const int grow = (r & 3) + 8 * (r >> 2) + rbase;
        const int row = bm * 256 + wm * 128 + rt * 32 + grow;
        const float g = accg[rt][r];
        const float u = accu[rt][r];
        const float s = g / (1.0f + __expf(-g));
        Inter[(long)row * FFN + col] = f2b(s * u);
      }
    asm volatile("s_waitcnt vmcnt(0)" ::: "memory");
  }
}

// ============ down GEMM-BT: 256x256, BK=64, 8 waves, 32x32 MFMA (1 round) ============
__global__ __launch_bounds__(512, 2)
void down256_kernel(const unsigned short* __restrict__ Inter,
                    const unsigned short* __restrict__ W2t,
                    float* __restrict__ Out) {
  __shared__ unsigned short sh[65536];
  const int tid = threadIdx.x, lane = tid & 63, wid = tid >> 6;
  const int wm = wid >> 2, wn = wid & 3;
  const int swz2 = xcd_chunk(blockIdx.x, (TOKENS / 256) * (HIDDEN / 256));  // 256
  const int bm = swz2 & 15;
  const int bn = swz2 >> 4;
  const int sr = tid >> 3;
  const int scb = (((tid & 7) ^ (sr & 7)) << 4);
  const int l31 = lane & 31;
  const int kb16 = (lane >> 5) * 16;
  const int swz = (lane & 7) << 4;

  const unsigned short* Ap = Inter + (long)(bm * 256) * FFN;
  const unsigned short* Bp = W2t + (long)(bn * 256) * FFN;

  f32x16 acc[4][2] = {};

  auto STAGE = [&](int kind, int h, int buf, int t) {
    const unsigned short* src = (kind ? Bp : Ap) + (long)(h * 128 + sr) * FFN + t * 64 + (scb >> 1);
    unsigned short* dst = sh + buf * 32768 + kind * 16384 + h * 8192 + tid * 8;
    __builtin_amdgcn_global_load_lds((gbl_void_t*)src, (lds_void_t*)dst, 16, 0, 0);
    __builtin_amdgcn_global_load_lds((gbl_void_t*)(src + 64L * FFN), (lds_void_t*)(dst + 4096), 16, 0, 0);
  };
  auto LDA4 = [&](bf16x8* a, int buf, int kb) {
    const char* base = (const char*)sh + buf * 65536 + (wm * 128 + l31) * 128 + ((kb + kb16) ^ swz);
#pragma unroll
    for (int rt = 0; rt < 4; ++rt) a[rt] = *(const bf16x8*)(base + rt * 32 * 128);
  };
  auto LDB1 = [&](bf16x8& b, int buf, int ct, int kb) {
    const int hrow = wn * 64 + ct * 32 + l31;  // 0..255
    const char* base = (const char*)sh + buf * 65536 + 32768 + (hrow >> 7) * 16384 +
                       (hrow & 127) * 128 + ((kb + kb16) ^ swz);
    b = *(const bf16x8*)(base);
  };

  STAGE(0, 0, 0, 0); STAGE(0, 1, 0, 0); STAGE(1, 0, 0, 0); STAGE(1, 1, 0, 0);

  bf16x8 a0[4], a1[4], b0, b1;
  const int NT = FFN / 64;  // 224
  for (int t = 0; t < NT; ++t) {
    const int cur = t & 1, nxt = cur ^ 1;
    const bool pre = (t + 1 < NT);
    // P0: prefetch B(t+1); gate vmcnt(4); MFMA ct0 ks0+ks1
    if (pre) { STAGE(1, 0, nxt, t + 1); STAGE(1, 1, nxt, t + 1);
               asm volatile("s_waitcnt vmcnt(4)" ::: "memory"); }
    else     { asm volatile("s_waitcnt vmcnt(0)" ::: "memory"); }
    SBAR();
    LDA4(a0, cur, 0); LDA4(a1, cur, 32); LDB1(b0, cur, 0, 0); LDB1(b1, cur, 0, 32);
    __builtin_amdgcn_s_setprio(1);
#pragma unroll
    for (int rt = 0; rt < 4; ++rt) {
      acc[rt][0] = MFMA32(a0[rt], b0, acc[rt][0]);
      acc[rt][0] = MFMA32(a1[rt], b1, acc[rt][0]);
    }
    __builtin_amdgcn_s_setprio(0);
    SBAR();
    // P1: prefetch A(t+1); MFMA ct1 ks0+ks1
    if (pre) { STAGE(0, 0, nxt, t + 1); STAGE(0, 1, nxt, t + 1); }
    LDB1(b0, cur, 1, 0); LDB1(b1, cur, 1, 32);
    __builtin_amdgcn_s_setprio(1);
#pragma unroll
    for (int rt = 0; rt < 4; ++rt) {
      acc[rt][1] = MFMA32(a0[rt], b0, acc[rt][1]);
      acc[rt][1] = MFMA32(a1[rt], b1, acc[rt][1]);
    }
    __builtin_amdgcn_s_setprio(0);
    SBAR();
    // P2: MFMA ct0 ks2+ks3
    LDA4(a0, cur, 64); LDA4(a1, cur, 96); LDB1(b0, cur, 0, 64); LDB1(b1, cur, 0, 96);
    __builtin_amdgcn_s_setprio(1);
#pragma unroll
    for (int rt = 0; rt < 4; ++rt) {
      acc[rt][0] = MFMA32(a0[rt], b0, acc[rt][0]);
      acc[rt][0] = MFMA32(a1[rt], b1, acc[rt][0]);
    }
    __builtin_amdgcn_s_setprio(0);
    SBAR();
    // P3: MFMA ct1 ks2+ks3
    LDB1(b0, cur, 1, 64); LDB1(b1, cur, 1, 96);
    __builtin_amdgcn_s_setprio(1);
#pragma unroll
    for (int rt = 0; rt < 4; ++rt) {
      acc[rt][1] = MFMA32(a0[rt], b0, acc[rt][1]);
      acc[rt][1] = MFMA32(a1[rt], b1, acc[rt][1]);
    }
    __builtin_amdgcn_s_setprio(0);
    SBAR();
  }
  const int rbase = 4 * (lane >> 5);
#pragma unroll
  for (int rt = 0; rt < 4; ++rt)
#pragma unroll
    for (int ct = 0; ct < 2; ++ct) {
      const int col = bn * 256 + wn * 64 + ct * 32 + l31;
#pragma unroll
      for (int r = 0; r < 16; ++r) {
        const int grow = (r & 3) + 8 * (r >> 2) + rbase;
        const int row = bm * 256 + wm * 128 + rt * 32 + grow;
        Out[(long)row * HIDDEN + col] = acc[rt][ct][r];
      }
    }
}

// ---- fallback down (round-2 verified, 16x16) when ws lacks w2t space ----
__device__ __forceinline__ void stage_tile_128(const unsigned short* __restrict__ g, long ldk,
                                               unsigned short* lds, int wave, int lane) {
#pragma unroll
  for (int it = 0; it < 2; ++it) {
    const int row = (it * 4 + wave) * 16 + (lane >> 2);
    const int kcol = (lane & 3) * 8;
    const unsigned short* src = g + (long)row * ldk + kcol;
    unsigned short* dst = lds + row * 32 + kcol;
    __builtin_amdgcn_global_load_lds((gbl_void_t*)src, (lds_void_t*)dst, 16, 0, 0);
  }
}

__global__ __launch_bounds__(256, 2)
void down_nt_kernel(const unsigned short* __restrict__ Inter,
                    const float* __restrict__ W2,
                    float* __restrict__ Out) {
  __shared__ unsigned short As[128 * 32];
  __shared__ unsigned short Bs[128 * 32];
  const int t = threadIdx.x;
  const int lane = t & 63;
  const int wave = t >> 6;
  const int bm = blockIdx.x & 31;
  const int bn = blockIdx.x >> 5;
  const int wm = (wave >> 1) * 64;
  const int wn = (wave & 1) * 64;
  const unsigned short* gA = Inter + (long)(bm * 128) * FFN;

  f32x4 acc[4][4] = {};
  const int fr = lane & 15;
  const int kg = (lane >> 4) * 8;
  const int p = lane & 15;
  const int h0 = wave * 32 + (lane >> 4) * 8;
  const float* gB = W2 + bn * 128 + h0;

  for (int kt = 0; kt < FFN; kt += 32) {
    __syncthreads();
    stage_tile_128(gA + kt, FFN, As, wave, lane);
    const float* r0p = gB + (long)(kt + 2 * p) * HIDDEN;
    const float* r1p = r0p + HIDDEN;
    const float4 a0 = *reinterpret_cast<const float4*>(r0p);
    const float4 a1 = *reinterpret_cast<const float4*>(r0p + 4);
    const float4 b0 = *reinterpret_cast<const float4*>(r1p);
    const float4 b1 = *reinterpret_cast<const float4*>(r1p + 4);
    unsigned short lo[8], hi[8];
    lo[0] = f2b(a0.x); lo[1] = f2b(a0.y); lo[2] = f2b(a0.z); lo[3] = f2b(a0.w);
    lo[4] = f2b(a1.x); lo[5] = f2b(a1.y); lo[6] = f2b(a1.z); lo[7] = f2b(a1.w);
    hi[0] = f2b(b0.x); hi[1] = f2b(b0.y); hi[2] = f2b(b0.z); hi[3] = f2b(b0.w);
    hi[4] = f2b(b1.x); hi[5] = f2b(b1.y); hi[6] = f2b(b1.z); hi[7] = f2b(b1.w);
#pragma unroll
    for (int j = 0; j < 8; ++j) {
      const unsigned int pack = (unsigned int)lo[j] | ((unsigned int)hi[j] << 16);
      *reinterpret_cast<unsigned int*>(&Bs[(h0 + j) * 32 + 2 * p]) = pack;
    }
    __syncthreads();
    bf16x8 a[4], b[4];
#pragma unroll
    for (int m = 0; m < 4; ++m)
      a[m] = *reinterpret_cast<const bf16x8*>(&As[(wm + m * 16 + fr) * 32 + kg]);
#pragma unroll
    for (int n = 0; n < 4; ++n)
      b[n] = *reinterpret_cast<const bf16x8*>(&Bs[(wn + n * 16 + fr) * 32 + kg]);
#pragma unroll
    for (int m = 0; m < 4; ++m)
#pragma unroll
      for (int n = 0; n < 4; ++n)
        acc[m][n] = MFMA16(a[m], b[n], acc[m][n]);
  }
  const int r0 = (lane >> 4) * 4;
#pragma unroll
  for (int m = 0; m < 4; ++m)
#pragma unroll
    for (int n = 0; n < 4; ++n)
#pragma unroll
      for (int r = 0; r < 4; ++r) {
        const int row = bm * 128 + wm + m * 16 + r0 + r;
        const int col = bn * 128 + wn + n * 16 + fr;
        Out[(long)row * HIDDEN + col] = acc[m][n][r];
      }
}

extern "C" void kernel_launch(void* const* d_in, const int* in_sizes, int n_in,
                              void* d_out, int out_size, void* d_ws, size_t ws_size,
                              hipStream_t stream) {
  const float* x  = (const float*)d_in[0];
  const float* w1 = (const float*)d_in[1];
  const float* v1 = (const float*)d_in[2];
  const float* w2 = (const float*)d_in[3];
  float* out = (float*)d_out;

  // ws layout (bytes): xb 33,554,432 | w1b 117,440,512 | v1b 117,440,512 |
  //                    inter 117,440,512 | w2t 117,440,512  -> 503,316,480 total.
  const size_t REQ_SMALL = 385875968UL;
  const size_t REQ_FULL  = 503316480UL;
  if (ws_size < REQ_SMALL) return;
  const bool full = (ws_size >= REQ_FULL);
  char* ws = (char*)d_ws;
  unsigned short* xb     = (unsigned short*)(ws);
  unsigned short* w1b    = (unsigned short*)(ws + 33554432L);
  unsigned short* v1b    = (unsigned short*)(ws + 150994944L);
  unsigned short* interb = (unsigned short*)(ws + 268435456L);
  unsigned short* w2tb   = (unsigned short*)(ws + 385875968L);

  hipLaunchKernelGGL(cvt_kernel, dim3(2048), dim3(256), 0, stream, x,  xb,  (long)TOKENS * HIDDEN);
  hipLaunchKernelGGL(cvt_kernel, dim3(2048), dim3(256), 0, stream, w1, w1b, (long)FFN * HIDDEN);
  hipLaunchKernelGGL(cvt_kernel, dim3(2048), dim3(256), 0, stream, v1, v1b, (long)FFN * HIDDEN);
  if (full)
    hipLaunchKernelGGL(transpose_cvt_kernel, dim3(FFN / 64, HIDDEN / 64), dim3(256), 0, stream, w2, w2tb);
  hipLaunchKernelGGL(gateup256p_kernel, dim3(256), dim3(512), 0, stream,
                     xb, w1b, v1b, interb);
  if (full)
    hipLaunchKernelGGL(down256_kernel, dim3((TOKENS / 256) * (HIDDEN / 256)), dim3(512), 0, stream,
                       interb, w2tb, out);
  else
    hipLaunchKernelGGL(down_nt_kernel, dim3((TOKENS / 128) * (HIDDEN / 128)), dim3(256), 0, stream,
                       interb, w2, out);
}

// Round 14
// 1411.982 us; speedup vs baseline: 1.1356x; 1.1356x over previous
//
#include <hip/hip_runtime.h>
#include <hip/hip_bf16.h>
#include <stdint.h>

// DbrxExpertGLU: down = (silu(x@w1^T) * (x@v1^T)) @ w2
// T=4096, H=4096, F=14336. fp32 in/out; bf16 MFMA compute.
// R14 = R12 bodies (16x16 MFMA; R13's 32x32 reverted — 8.8e7 bank conflicts)
// + gateup W/V TRIPLE-buffer with 2-tile prefetch lead (weights are the only
// non-L3-resident stream; 1-tile lead ~1100cyc barely covers ~900cyc HBM).
// LDS 160KB exactly (A dbuf 64KB + WV tribuf 96KB).
#define TOKENS 4096
#define HIDDEN 4096
#define FFN    14336

typedef __attribute__((ext_vector_type(8))) short bf16x8;
typedef __attribute__((ext_vector_type(4))) float f32x4;
typedef __attribute__((ext_vector_type(8))) unsigned short u16x8;

typedef __attribute__((address_space(3))) void lds_void_t;
typedef const __attribute__((address_space(1))) void gbl_void_t;

static __device__ __forceinline__ unsigned short f2b(float f) {
  union { float f; unsigned int u; } v; v.f = f;
  unsigned int u = v.u;
  return (unsigned short)((u + 0x7FFFu + ((u >> 16) & 1u)) >> 16);  // RNE
}

// ---------------- fp32 -> bf16 convert ----------------
__global__ void cvt_kernel(const float* __restrict__ in, unsigned short* __restrict__ out, long n) {
  long idx = (long)blockIdx.x * blockDim.x + threadIdx.x;
  long stride = (long)gridDim.x * blockDim.x;
  for (long i = idx * 4; i < n; i += stride * 4) {
    const float4 v = *reinterpret_cast<const float4*>(in + i);
    ushort4 o;
    o.x = f2b(v.x); o.y = f2b(v.y); o.z = f2b(v.z); o.w = f2b(v.w);
    *reinterpret_cast<ushort4*>(out + i) = o;
  }
}

// ------- w2 [F][H] fp32 -> w2t [H][F] bf16 -------
__global__ void transpose_cvt_kernel(const float* __restrict__ in, unsigned short* __restrict__ out) {
  __shared__ float tile[64][65];
  const int f0 = blockIdx.x * 64;
  const int h0 = blockIdx.y * 64;
  const int t = threadIdx.x;
  const int rcol = (t & 15) * 4;
  const int rrow = t >> 4;
#pragma unroll
  for (int it = 0; it < 4; ++it) {
    int r = rrow + it * 16;
    const float4 v = *reinterpret_cast<const float4*>(in + (long)(f0 + r) * HIDDEN + h0 + rcol);
    tile[r][rcol] = v.x; tile[r][rcol + 1] = v.y; tile[r][rcol + 2] = v.z; tile[r][rcol + 3] = v.w;
  }
  __syncthreads();
  const int wrow = t >> 2;
  const int wc = (t & 3) * 16;
  u16x8 lo, hi;
#pragma unroll
  for (int j = 0; j < 8; ++j) lo[j] = f2b(tile[wc + j][wrow]);
#pragma unroll
  for (int j = 0; j < 8; ++j) hi[j] = f2b(tile[wc + 8 + j][wrow]);
  u16x8* dst = reinterpret_cast<u16x8*>(out + (long)(h0 + wrow) * FFN + f0 + wc);
  dst[0] = lo; dst[1] = hi;
}

#define MFMA16(a, b, c) __builtin_amdgcn_mfma_f32_16x16x32_bf16((a), (b), (c), 0, 0, 0)
#define SBAR()  __builtin_amdgcn_s_barrier()

static __device__ __forceinline__ int xcd_chunk(int bid, int nwg) {
  return (bid & 7) * (nwg >> 3) + (bid >> 3);
}

// ============ persistent fused gate/up: grid 256, 7 F-tiles/block ============
// LDS 160KB: A dbuf 2x32KB @0 | WV tribuf 3x32KB (W16K+V16K) @64KB.
// Chronology per tile t: gate vmcnt(4) [allows newest 4 = WV(t+1)] -> barrier
// -> issue A(t+1) -> P1 issues WV(t+2). So vmcnt(4) always drains A(t)+WV(t).
__global__ __launch_bounds__(512, 2)
void gateup256p_kernel(const unsigned short* __restrict__ X,
                       const unsigned short* __restrict__ W1,
                       const unsigned short* __restrict__ V1,
                       unsigned short* __restrict__ Inter) {
  __shared__ unsigned short sh[81920];  // 160 KB
  const int tid = threadIdx.x, lane = tid & 63, wid = tid >> 6;
  const int wm = wid >> 2, wn = wid & 3;
  const int p = blockIdx.x;           // 0..255, one block per CU
  const int bm = p & 15;              // T-tile (fixed per block)
  const int bnl = p >> 4;             // bn lane 0..15
  const int sr = tid >> 3;
  const int scb = (((tid & 7) ^ (sr & 7)) << 4);
  const int l15 = lane & 15;
  const int cb0 = (((lane >> 4) * 16) ^ ((lane & 7) << 4));
  const int cb1 = ((64 + (lane >> 4) * 16) ^ ((lane & 7) << 4));

  const unsigned short* Ap = X + (long)(bm * 256) * HIDDEN;

  auto LDA8 = [&](bf16x8* a, int bufA, int cb) {
    const char* base = (const char*)sh + bufA * 32768 + wm * 16384 + l15 * 128 + cb;
#pragma unroll
    for (int m = 0; m < 8; ++m) a[m] = *(const bf16x8*)(base + m * 2048);
  };
  auto LDW2 = [&](bf16x8* w, int b3, int cb) {
    const char* base = (const char*)sh + 65536 + b3 * 32768 + (wn * 32 + l15) * 128 + cb;
    w[0] = *(const bf16x8*)(base);
    w[1] = *(const bf16x8*)(base + 2048);
  };
  auto LDV2 = [&](bf16x8* v, int b3, int cb) {
    const char* base = (const char*)sh + 65536 + b3 * 32768 + 16384 + (wn * 32 + l15) * 128 + cb;
    v[0] = *(const bf16x8*)(base);
    v[1] = *(const bf16x8*)(base + 2048);
  };

  for (int j = 0; j < 7; ++j) {
    const int bn = j * 16 + bnl;      // 16 bm-blocks share panel bn concurrently
    const unsigned short* Wp = W1 + (long)(bn * 128) * HIDDEN;
    const unsigned short* Vp = V1 + (long)(bn * 128) * HIDDEN;

    auto STA = [&](int u, int bufA, int t) {   // A unit u: 64 rows, 8KB
      const unsigned short* src = Ap + (long)(u * 64 + sr) * HIDDEN + t * 64 + (scb >> 1);
      unsigned short* dst = sh + bufA * 16384 + u * 4096 + tid * 8;
      __builtin_amdgcn_global_load_lds((gbl_void_t*)src, (lds_void_t*)dst, 16, 0, 0);
    };
    auto STW = [&](int u, int b3, int t) {     // W unit u: 64 rows, 8KB
      const unsigned short* src = Wp + (long)(u * 64 + sr) * HIDDEN + t * 64 + (scb >> 1);
      unsigned short* dst = sh + 32768 + b3 * 16384 + u * 4096 + tid * 8;
      __builtin_amdgcn_global_load_lds((gbl_void_t*)src, (lds_void_t*)dst, 16, 0, 0);
    };
    auto STV = [&](int u, int b3, int t) {
      const unsigned short* src = Vp + (long)(u * 64 + sr) * HIDDEN + t * 64 + (scb >> 1);
      unsigned short* dst = sh + 32768 + b3 * 16384 + 8192 + u * 4096 + tid * 8;
      __builtin_amdgcn_global_load_lds((gbl_void_t*)src, (lds_void_t*)dst, 16, 0, 0);
    };

    f32x4 accg[8][2] = {};
    f32x4 accu[8][2] = {};

    // prologue (chronological): WV(0)->b3=0 ; A(0)->bufA=0 ; WV(1)->b3=1
    STW(0, 0, 0); STW(1, 0, 0); STV(0, 0, 0); STV(1, 0, 0);
    STA(0, 0, 0); STA(1, 0, 0); STA(2, 0, 0); STA(3, 0, 0);
    STW(0, 1, 1); STW(1, 1, 1); STV(0, 1, 1); STV(1, 1, 1);

    bf16x8 a[8], w[2], v[2];
    const int NT = HIDDEN / 64;  // 64
    for (int t = 0; t < NT; ++t) {
      const int curA = t & 1, nxtA = curA ^ 1;
      const int b3 = t % 3, b3w = (t + 2) % 3;
      // gate: newest 4 in flight = WV(t+1); drains A(t) and WV(t)
      if (t + 1 < NT) { asm volatile("s_waitcnt vmcnt(4)" ::: "memory"); }
      else            { asm volatile("s_waitcnt vmcnt(0)" ::: "memory"); }
      SBAR();
      if (t + 1 < NT) { STA(0, nxtA, t + 1); STA(1, nxtA, t + 1);
                        STA(2, nxtA, t + 1); STA(3, nxtA, t + 1); }
      // P0: kk0 x W
      LDA8(a, curA, cb0); LDW2(w, b3, cb0);
      __builtin_amdgcn_s_setprio(1);
#pragma unroll
      for (int m = 0; m < 8; ++m) {
        accg[m][0] = MFMA16(a[m], w[0], accg[m][0]);
        accg[m][1] = MFMA16(a[m], w[1], accg[m][1]);
      }
      __builtin_amdgcn_s_setprio(0);
      SBAR();
      // P1: issue WV(t+2) (2-tile lead, HBM-latency cover); kk0 x V
      if (t + 2 < NT) { STW(0, b3w, t + 2); STW(1, b3w, t + 2);
                        STV(0, b3w, t + 2); STV(1, b3w, t + 2); }
      LDV2(v, b3, cb0);
      __builtin_amdgcn_s_setprio(1);
#pragma unroll
      for (int m = 0; m < 8; ++m) {
        accu[m][0] = MFMA16(a[m], v[0], accu[m][0]);
        accu[m][1] = MFMA16(a[m], v[1], accu[m][1]);
      }
      __builtin_amdgcn_s_setprio(0);
      SBAR();
      // P2: kk1 x W
      LDA8(a, curA, cb1); LDW2(w, b3, cb1);
      __builtin_amdgcn_s_setprio(1);
#pragma unroll
      for (int m = 0; m < 8; ++m) {
        accg[m][0] = MFMA16(a[m], w[0], accg[m][0]);
        accg[m][1] = MFMA16(a[m], w[1], accg[m][1]);
      }
      __builtin_amdgcn_s_setprio(0);
      SBAR();
      // P3: kk1 x V
      LDV2(v, b3, cb1);
      __builtin_amdgcn_s_setprio(1);
#pragma unroll
      for (int m = 0; m < 8; ++m) {
        accu[m][0] = MFMA16(a[m], v[0], accu[m][0]);
        accu[m][1] = MFMA16(a[m], v[1], accu[m][1]);
      }
      __builtin_amdgcn_s_setprio(0);
      SBAR();
    }
    // epilogue: silu(g)*u -> bf16. C/D map: col=lane&15, row=(lane>>4)*4+r (m89)
    const int r0 = (lane >> 4) * 4;
#pragma unroll
    for (int m = 0; m < 8; ++m)
#pragma unroll
      for (int n = 0; n < 2; ++n)
#pragma unroll
        for (int r = 0; r < 4; ++r) {
          const float g = accg[m][n][r];
          const float u = accu[m][n][r];
          const float s = g / (1.0f + __expf(-g));
          const int row = bm * 256 + wm * 128 + m * 16 + r0 + r;
          const int col = bn * 128 + wn * 32 + n * 16 + l15;
          Inter[(long)row * FFN + col] = f2b(s * u);
        }
    // drain epilogue stores so the next group's vmcnt ledger starts clean
    asm volatile("s_waitcnt vmcnt(0)" ::: "memory");
  }
}

// ============ down GEMM-BT, 8-phase: 256x256, BK=64, 8 waves (R12 body) ============
__global__ __launch_bounds__(512, 2)
void down256_kernel(const unsigned short* __restrict__ Inter,
                    const unsigned short* __restrict__ W2t,
                    float* __restrict__ Out) {
  __shared__ unsigned short sh[65536];
  const int tid = threadIdx.x, lane = tid & 63, wid = tid >> 6;
  const int wm = wid >> 2, wn = wid & 3;
  const int swz = xcd_chunk(blockIdx.x, (TOKENS / 256) * (HIDDEN / 256));  // 256
  const int bm = swz & 15;
  const int bn = swz >> 4;
  const int sr = tid >> 3;
  const int scb = (((tid & 7) ^ (sr & 7)) << 4);
  const int l15 = lane & 15;
  const int cb0 = (((lane >> 4) * 16) ^ ((lane & 7) << 4));
  const int cb1 = ((64 + (lane >> 4) * 16) ^ ((lane & 7) << 4));

  const unsigned short* Ap = Inter + (long)(bm * 256) * FFN;
  const unsigned short* Bp = W2t + (long)(bn * 256) * FFN;

  f32x4 acc[8][4] = {};

  auto STAGE = [&](int kind, int h, int buf, int t) {
    const unsigned short* src = (kind ? Bp : Ap) + (long)(h * 128 + sr) * FFN + t * 64 + (scb >> 1);
    unsigned short* dst = sh + buf * 32768 + kind * 16384 + h * 8192 + tid * 8;
    __builtin_amdgcn_global_load_lds((gbl_void_t*)src, (lds_void_t*)dst, 16, 0, 0);
    __builtin_amdgcn_global_load_lds((gbl_void_t*)(src + 64L * FFN), (lds_void_t*)(dst + 4096), 16, 0, 0);
  };
  auto LDA8 = [&](bf16x8* a, int buf, int cb) {
    const char* base = (const char*)sh + buf * 65536 + wm * 16384 + l15 * 128 + cb;
#pragma unroll
    for (int m = 0; m < 8; ++m) a[m] = *(const bf16x8*)(base + m * 2048);
  };
  auto LDB2 = [&](bf16x8* b, int buf, int cb, int np) {
    const char* base = (const char*)sh + buf * 65536 + 32768 + (wn >> 1) * 16384 +
                       ((wn & 1) * 64 + l15) * 128 + cb;
    b[2 * np]     = *(const bf16x8*)(base + (2 * np) * 2048);
    b[2 * np + 1] = *(const bf16x8*)(base + (2 * np + 1) * 2048);
  };

  STAGE(0, 0, 0, 0); STAGE(0, 1, 0, 0); STAGE(1, 0, 0, 0); STAGE(1, 1, 0, 0);

  bf16x8 a[8], b[4];
  const int NT = FFN / 64;  // 224
  for (int t = 0; t < NT; ++t) {
    const int cur = t & 1, nxt = cur ^ 1;
    const bool pre = (t + 1 < NT);
    // P0: prefetch B(t+1); gate vmcnt(4); MFMA n01 kk0
    if (pre) { STAGE(1, 0, nxt, t + 1); STAGE(1, 1, nxt, t + 1);
               asm volatile("s_waitcnt vmcnt(4)" ::: "memory"); }
    else     { asm volatile("s_waitcnt vmcnt(0)" ::: "memory"); }
    SBAR();
    LDA8(a, cur, cb0); LDB2(b, cur, cb0, 0);
    __builtin_amdgcn_s_setprio(1);
#pragma unroll
    for (int m = 0; m < 8; ++m) {
      acc[m][0] = MFMA16(a[m], b[0], acc[m][0]);
      acc[m][1] = MFMA16(a[m], b[1], acc[m][1]);
    }
    __builtin_amdgcn_s_setprio(0);
    SBAR();
    // P1: prefetch A(t+1); MFMA n23 kk0
    if (pre) { STAGE(0, 0, nxt, t + 1); STAGE(0, 1, nxt, t + 1); }
    LDB2(b, cur, cb0, 1);
    __builtin_amdgcn_s_setprio(1);
#pragma unroll
    for (int m = 0; m < 8; ++m) {
      acc[m][2] = MFMA16(a[m], b[2], acc[m][2]);
      acc[m][3] = MFMA16(a[m], b[3], acc[m][3]);
    }
    __builtin_amdgcn_s_setprio(0);
    SBAR();
    // P2: MFMA n01 kk1
    LDA8(a, cur, cb1); LDB2(b, cur, cb1, 0);
    __builtin_amdgcn_s_setprio(1);
#pragma unroll
    for (int m = 0; m < 8; ++m) {
      acc[m][0] = MFMA16(a[m], b[0], acc[m][0]);
      acc[m][1] = MFMA16(a[m], b[1], acc[m][1]);
    }
    __builtin_amdgcn_s_setprio(0);
    SBAR();
    // P3: MFMA n23 kk1
    LDB2(b, cur, cb1, 1);
    __builtin_amdgcn_s_setprio(1);
#pragma unroll
    for (int m = 0; m < 8; ++m) {
      acc[m][2] = MFMA16(a[m], b[2], acc[m][2]);
      acc[m][3] = MFMA16(a[m], b[3], acc[m][3]);
    }
    __builtin_amdgcn_s_setprio(0);
    SBAR();
  }
  const int r0 = (lane >> 4) * 4;
#pragma unroll
  for (int m = 0; m < 8; ++m)
#pragma unroll
    for (int n = 0; n < 4; ++n)
#pragma unroll
      for (int r = 0; r < 4; ++r) {
        const int row = bm * 256 + wm * 128 + m * 16 + r0 + r;
        const int col = bn * 256 + wn * 64 + n * 16 + l15;
        Out[(long)row * HIDDEN + col] = acc[m][n][r];
      }
}

// ---- fallback down (round-2 verified) when ws lacks w2t space ----
__device__ __forceinline__ void stage_tile_128(const unsigned short* __restrict__ g, long ldk,
                                               unsigned short* lds, int wave, int lane) {
#pragma unroll
  for (int it = 0; it < 2; ++it) {
    const int row = (it * 4 + wave) * 16 + (lane >> 2);
    const int kcol = (lane & 3) * 8;
    const unsigned short* src = g + (long)row * ldk + kcol;
    unsigned short* dst = lds + row * 32 + kcol;
    __builtin_amdgcn_global_load_lds((gbl_void_t*)src, (lds_void_t*)dst, 16, 0, 0);
  }
}

__global__ __launch_bounds__(256, 2)
void down_nt_kernel(const unsigned short* __restrict__ Inter,
                    const float* __restrict__ W2,
                    float* __restrict__ Out) {
  __shared__ unsigned short As[128 * 32];
  __shared__ unsigned short Bs[128 * 32];
  const int t = threadIdx.x;
  const int lane = t & 63;
  const int wave = t >> 6;
  const int bm = blockIdx.x & 31;
  const int bn = blockIdx.x >> 5;
  const int wm = (wave >> 1) * 64;
  const int wn = (wave & 1) * 64;
  const unsigned short* gA = Inter + (long)(bm * 128) * FFN;

  f32x4 acc[4][4] = {};
  const int fr = lane & 15;
  const int kg = (lane >> 4) * 8;
  const int p = lane & 15;
  const int h0 = wave * 32 + (lane >> 4) * 8;
  const float* gB = W2 + bn * 128 + h0;

  for (int kt = 0; kt < FFN; kt += 32) {
    __syncthreads();
    stage_tile_128(gA + kt, FFN, As, wave, lane);
    const float* r0p = gB + (long)(kt + 2 * p) * HIDDEN;
    const float* r1p = r0p + HIDDEN;
    const float4 a0 = *reinterpret_cast<const float4*>(r0p);
    const float4 a1 = *reinterpret_cast<const float4*>(r0p + 4);
    const float4 b0 = *reinterpret_cast<const float4*>(r1p);
    const float4 b1 = *reinterpret_cast<const float4*>(r1p + 4);
    unsigned short lo[8], hi[8];
    lo[0] = f2b(a0.x); lo[1] = f2b(a0.y); lo[2] = f2b(a0.z); lo[3] = f2b(a0.w);
    lo[4] = f2b(a1.x); lo[5] = f2b(a1.y); lo[6] = f2b(a1.z); lo[7] = f2b(a1.w);
    hi[0] = f2b(b0.x); hi[1] = f2b(b0.y); hi[2] = f2b(b0.z); hi[3] = f2b(b0.w);
    hi[4] = f2b(b1.x); hi[5] = f2b(b1.y); hi[6] = f2b(b1.z); hi[7] = f2b(b1.w);
#pragma unroll
    for (int j = 0; j < 8; ++j) {
      const unsigned int pack = (unsigned int)lo[j] | ((unsigned int)hi[j] << 16);
      *reinterpret_cast<unsigned int*>(&Bs[(h0 + j) * 32 + 2 * p]) = pack;
    }
    __syncthreads();
    bf16x8 a[4], b[4];
#pragma unroll
    for (int m = 0; m < 4; ++m)
      a[m] = *reinterpret_cast<const bf16x8*>(&As[(wm + m * 16 + fr) * 32 + kg]);
#pragma unroll
    for (int n = 0; n < 4; ++n)
      b[n] = *reinterpret_cast<const bf16x8*>(&Bs[(wn + n * 16 + fr) * 32 + kg]);
#pragma unroll
    for (int m = 0; m < 4; ++m)
#pragma unroll
      for (int n = 0; n < 4; ++n)
        acc[m][n] = MFMA16(a[m], b[n], acc[m][n]);
  }
  const int r0 = (lane >> 4) * 4;
#pragma unroll
  for (int m = 0; m < 4; ++m)
#pragma unroll
    for (int n = 0; n < 4; ++n)
#pragma unroll
      for (int r = 0; r < 4; ++r) {
        const int row = bm * 128 + wm + m * 16 + r0 + r;
        const int col = bn * 128 + wn + n * 16 + fr;
        Out[(long)row * HIDDEN + col] = acc[m][n][r];
      }
}

extern "C" void kernel_launch(void* const* d_in, const int* in_sizes, int n_in,
                              void* d_out, int out_size, void* d_ws, size_t ws_size,
                              hipStream_t stream) {
  const float* x  = (const float*)d_in[0];
  const float* w1 = (const float*)d_in[1];
  const float* v1 = (const float*)d_in[2];
  const float* w2 = (const float*)d_in[3];
  float* out = (float*)d_out;

  // ws layout (bytes): xb 33,554,432 | w1b 117,440,512 | v1b 117,440,512 |
  //                    inter 117,440,512 | w2t 117,440,512  -> 503,316,480 total.
  const size_t REQ_SMALL = 385875968UL;
  const size_t REQ_FULL  = 503316480UL;
  if (ws_size < REQ_SMALL) return;
  const bool full = (ws_size >= REQ_FULL);
  char* ws = (char*)d_ws;
  unsigned short* xb     = (unsigned short*)(ws);
  unsigned short* w1b    = (unsigned short*)(ws + 33554432L);
  unsigned short* v1b    = (unsigned short*)(ws + 150994944L);
  unsigned short* interb = (unsigned short*)(ws + 268435456L);
  unsigned short* w2tb   = (unsigned short*)(ws + 385875968L);

  hipLaunchKernelGGL(cvt_kernel, dim3(2048), dim3(256), 0, stream, x,  xb,  (long)TOKENS * HIDDEN);
  hipLaunchKernelGGL(cvt_kernel, dim3(2048), dim3(256), 0, stream, w1, w1b, (long)FFN * HIDDEN);
  hipLaunchKernelGGL(cvt_kernel, dim3(2048), dim3(256), 0, stream, v1, v1b, (long)FFN * HIDDEN);
  if (full)
    hipLaunchKernelGGL(transpose_cvt_kernel, dim3(FFN / 64, HIDDEN / 64), dim3(256), 0, stream, w2, w2tb);
  hipLaunchKernelGGL(gateup256p_kernel, dim3(256), dim3(512), 0, stream,
                     xb, w1b, v1b, interb);
  if (full)
    hipLaunchKernelGGL(down256_kernel, dim3((TOKENS / 256) * (HIDDEN / 256)), dim3(512), 0, stream,
                       interb, w2tb, out);
  else
    hipLaunchKernelGGL(down_nt_kernel, dim3((TOKENS / 128) * (HIDDEN / 128)), dim3(256), 0, stream,
                       interb, w2, out);
}

// Round 15
// 1395.106 us; speedup vs baseline: 1.1493x; 1.0121x over previous
//
#include <hip/hip_runtime.h>
#include <hip/hip_bf16.h>
#include <stdint.h>

// DbrxExpertGLU: down = (silu(x@w1^T) * (x@v1^T)) @ w2
// T=4096, H=4096, F=14336. fp32 in/out; bf16 MFMA compute.
// R15 = R14 + producer/consumer temporal slicing: weight-cvt and gateup run in
// TWO interleaved halves so gateup always reads freshly-written (L3-hot)
// weights — the same residency advantage down256 gets from the transpose.
#define TOKENS 4096
#define HIDDEN 4096
#define FFN    14336

typedef __attribute__((ext_vector_type(8))) short bf16x8;
typedef __attribute__((ext_vector_type(4))) float f32x4;
typedef __attribute__((ext_vector_type(8))) unsigned short u16x8;

typedef __attribute__((address_space(3))) void lds_void_t;
typedef const __attribute__((address_space(1))) void gbl_void_t;

static __device__ __forceinline__ unsigned short f2b(float f) {
  union { float f; unsigned int u; } v; v.f = f;
  unsigned int u = v.u;
  return (unsigned short)((u + 0x7FFFu + ((u >> 16) & 1u)) >> 16);  // RNE
}

// ---------------- fp32 -> bf16 convert ----------------
__global__ void cvt_kernel(const float* __restrict__ in, unsigned short* __restrict__ out, long n) {
  long idx = (long)blockIdx.x * blockDim.x + threadIdx.x;
  long stride = (long)gridDim.x * blockDim.x;
  for (long i = idx * 4; i < n; i += stride * 4) {
    const float4 v = *reinterpret_cast<const float4*>(in + i);
    ushort4 o;
    o.x = f2b(v.x); o.y = f2b(v.y); o.z = f2b(v.z); o.w = f2b(v.w);
    *reinterpret_cast<ushort4*>(out + i) = o;
  }
}

// ------- w2 [F][H] fp32 -> w2t [H][F] bf16 -------
__global__ void transpose_cvt_kernel(const float* __restrict__ in, unsigned short* __restrict__ out) {
  __shared__ float tile[64][65];
  const int f0 = blockIdx.x * 64;
  const int h0 = blockIdx.y * 64;
  const int t = threadIdx.x;
  const int rcol = (t & 15) * 4;
  const int rrow = t >> 4;
#pragma unroll
  for (int it = 0; it < 4; ++it) {
    int r = rrow + it * 16;
    const float4 v = *reinterpret_cast<const float4*>(in + (long)(f0 + r) * HIDDEN + h0 + rcol);
    tile[r][rcol] = v.x; tile[r][rcol + 1] = v.y; tile[r][rcol + 2] = v.z; tile[r][rcol + 3] = v.w;
  }
  __syncthreads();
  const int wrow = t >> 2;
  const int wc = (t & 3) * 16;
  u16x8 lo, hi;
#pragma unroll
  for (int j = 0; j < 8; ++j) lo[j] = f2b(tile[wc + j][wrow]);
#pragma unroll
  for (int j = 0; j < 8; ++j) hi[j] = f2b(tile[wc + 8 + j][wrow]);
  u16x8* dst = reinterpret_cast<u16x8*>(out + (long)(h0 + wrow) * FFN + f0 + wc);
  dst[0] = lo; dst[1] = hi;
}

#define MFMA16(a, b, c) __builtin_amdgcn_mfma_f32_16x16x32_bf16((a), (b), (c), 0, 0, 0)
#define SBAR()  __builtin_amdgcn_s_barrier()

static __device__ __forceinline__ int xcd_chunk(int bid, int nwg) {
  return (bid & 7) * (nwg >> 3) + (bid >> 3);
}

// ============ persistent fused gate/up: grid 256, F-tiles j0..j1 per launch ============
// LDS 160KB: A dbuf 2x32KB @0 | WV tribuf 3x32KB (W16K+V16K) @64KB.
__global__ __launch_bounds__(512, 2)
void gateup256p_kernel(const unsigned short* __restrict__ X,
                       const unsigned short* __restrict__ W1,
                       const unsigned short* __restrict__ V1,
                       unsigned short* __restrict__ Inter,
                       int j0, int j1) {
  __shared__ unsigned short sh[81920];  // 160 KB
  const int tid = threadIdx.x, lane = tid & 63, wid = tid >> 6;
  const int wm = wid >> 2, wn = wid & 3;
  const int p = blockIdx.x;           // 0..255, one block per CU
  const int bm = p & 15;              // T-tile (fixed per block)
  const int bnl = p >> 4;             // bn lane 0..15
  const int sr = tid >> 3;
  const int scb = (((tid & 7) ^ (sr & 7)) << 4);
  const int l15 = lane & 15;
  const int cb0 = (((lane >> 4) * 16) ^ ((lane & 7) << 4));
  const int cb1 = ((64 + (lane >> 4) * 16) ^ ((lane & 7) << 4));

  const unsigned short* Ap = X + (long)(bm * 256) * HIDDEN;

  auto LDA8 = [&](bf16x8* a, int bufA, int cb) {
    const char* base = (const char*)sh + bufA * 32768 + wm * 16384 + l15 * 128 + cb;
#pragma unroll
    for (int m = 0; m < 8; ++m) a[m] = *(const bf16x8*)(base + m * 2048);
  };
  auto LDW2 = [&](bf16x8* w, int b3, int cb) {
    const char* base = (const char*)sh + 65536 + b3 * 32768 + (wn * 32 + l15) * 128 + cb;
    w[0] = *(const bf16x8*)(base);
    w[1] = *(const bf16x8*)(base + 2048);
  };
  auto LDV2 = [&](bf16x8* v, int b3, int cb) {
    const char* base = (const char*)sh + 65536 + b3 * 32768 + 16384 + (wn * 32 + l15) * 128 + cb;
    v[0] = *(const bf16x8*)(base);
    v[1] = *(const bf16x8*)(base + 2048);
  };

  for (int j = j0; j < j1; ++j) {
    const int bn = j * 16 + bnl;      // 16 bm-blocks share panel bn concurrently
    const unsigned short* Wp = W1 + (long)(bn * 128) * HIDDEN;
    const unsigned short* Vp = V1 + (long)(bn * 128) * HIDDEN;

    auto STA = [&](int u, int bufA, int t) {   // A unit u: 64 rows, 8KB
      const unsigned short* src = Ap + (long)(u * 64 + sr) * HIDDEN + t * 64 + (scb >> 1);
      unsigned short* dst = sh + bufA * 16384 + u * 4096 + tid * 8;
      __builtin_amdgcn_global_load_lds((gbl_void_t*)src, (lds_void_t*)dst, 16, 0, 0);
    };
    auto STW = [&](int u, int b3, int t) {     // W unit u: 64 rows, 8KB
      const unsigned short* src = Wp + (long)(u * 64 + sr) * HIDDEN + t * 64 + (scb >> 1);
      unsigned short* dst = sh + 32768 + b3 * 16384 + u * 4096 + tid * 8;
      __builtin_amdgcn_global_load_lds((gbl_void_t*)src, (lds_void_t*)dst, 16, 0, 0);
    };
    auto STV = [&](int u, int b3, int t) {
      const unsigned short* src = Vp + (long)(u * 64 + sr) * HIDDEN + t * 64 + (scb >> 1);
      unsigned short* dst = sh + 32768 + b3 * 16384 + 8192 + u * 4096 + tid * 8;
      __builtin_amdgcn_global_load_lds((gbl_void_t*)src, (lds_void_t*)dst, 16, 0, 0);
    };

    f32x4 accg[8][2] = {};
    f32x4 accu[8][2] = {};

    // prologue (chronological): WV(0)->b3=0 ; A(0)->bufA=0 ; WV(1)->b3=1
    STW(0, 0, 0); STW(1, 0, 0); STV(0, 0, 0); STV(1, 0, 0);
    STA(0, 0, 0); STA(1, 0, 0); STA(2, 0, 0); STA(3, 0, 0);
    STW(0, 1, 1); STW(1, 1, 1); STV(0, 1, 1); STV(1, 1, 1);

    bf16x8 a[8], w[2], v[2];
    const int NT = HIDDEN / 64;  // 64
    for (int t = 0; t < NT; ++t) {
      const int curA = t & 1, nxtA = curA ^ 1;
      const int b3 = t % 3, b3w = (t + 2) % 3;
      // gate: newest 4 in flight = WV(t+1); drains A(t) and WV(t)
      if (t + 1 < NT) { asm volatile("s_waitcnt vmcnt(4)" ::: "memory"); }
      else            { asm volatile("s_waitcnt vmcnt(0)" ::: "memory"); }
      SBAR();
      if (t + 1 < NT) { STA(0, nxtA, t + 1); STA(1, nxtA, t + 1);
                        STA(2, nxtA, t + 1); STA(3, nxtA, t + 1); }
      // P0: kk0 x W
      LDA8(a, curA, cb0); LDW2(w, b3, cb0);
      __builtin_amdgcn_s_setprio(1);
#pragma unroll
      for (int m = 0; m < 8; ++m) {
        accg[m][0] = MFMA16(a[m], w[0], accg[m][0]);
        accg[m][1] = MFMA16(a[m], w[1], accg[m][1]);
      }
      __builtin_amdgcn_s_setprio(0);
      SBAR();
      // P1: issue WV(t+2) (2-tile lead); kk0 x V
      if (t + 2 < NT) { STW(0, b3w, t + 2); STW(1, b3w, t + 2);
                        STV(0, b3w, t + 2); STV(1, b3w, t + 2); }
      LDV2(v, b3, cb0);
      __builtin_amdgcn_s_setprio(1);
#pragma unroll
      for (int m = 0; m < 8; ++m) {
        accu[m][0] = MFMA16(a[m], v[0], accu[m][0]);
        accu[m][1] = MFMA16(a[m], v[1], accu[m][1]);
      }
      __builtin_amdgcn_s_setprio(0);
      SBAR();
      // P2: kk1 x W
      LDA8(a, curA, cb1); LDW2(w, b3, cb1);
      __builtin_amdgcn_s_setprio(1);
#pragma unroll
      for (int m = 0; m < 8; ++m) {
        accg[m][0] = MFMA16(a[m], w[0], accg[m][0]);
        accg[m][1] = MFMA16(a[m], w[1], accg[m][1]);
      }
      __builtin_amdgcn_s_setprio(0);
      SBAR();
      // P3: kk1 x V
      LDV2(v, b3, cb1);
      __builtin_amdgcn_s_setprio(1);
#pragma unroll
      for (int m = 0; m < 8; ++m) {
        accu[m][0] = MFMA16(a[m], v[0], accu[m][0]);
        accu[m][1] = MFMA16(a[m], v[1], accu[m][1]);
      }
      __builtin_amdgcn_s_setprio(0);
      SBAR();
    }
    // epilogue: silu(g)*u -> bf16. C/D map: col=lane&15, row=(lane>>4)*4+r (m89)
    const int r0 = (lane >> 4) * 4;
#pragma unroll
    for (int m = 0; m < 8; ++m)
#pragma unroll
      for (int n = 0; n < 2; ++n)
#pragma unroll
        for (int r = 0; r < 4; ++r) {
          const float g = accg[m][n][r];
          const float u = accu[m][n][r];
          const float s = g / (1.0f + __expf(-g));
          const int row = bm * 256 + wm * 128 + m * 16 + r0 + r;
          const int col = bn * 128 + wn * 32 + n * 16 + l15;
          Inter[(long)row * FFN + col] = f2b(s * u);
        }
    // drain epilogue stores so the next group's vmcnt ledger starts clean
    asm volatile("s_waitcnt vmcnt(0)" ::: "memory");
  }
}

// ============ down GEMM-BT, 8-phase: 256x256, BK=64, 8 waves (R12 body) ============
__global__ __launch_bounds__(512, 2)
void down256_kernel(const unsigned short* __restrict__ Inter,
                    const unsigned short* __restrict__ W2t,
                    float* __restrict__ Out) {
  __shared__ unsigned short sh[65536];
  const int tid = threadIdx.x, lane = tid & 63, wid = tid >> 6;
  const int wm = wid >> 2, wn = wid & 3;
  const int swz = xcd_chunk(blockIdx.x, (TOKENS / 256) * (HIDDEN / 256));  // 256
  const int bm = swz & 15;
  const int bn = swz >> 4;
  const int sr = tid >> 3;
  const int scb = (((tid & 7) ^ (sr & 7)) << 4);
  const int l15 = lane & 15;
  const int cb0 = (((lane >> 4) * 16) ^ ((lane & 7) << 4));
  const int cb1 = ((64 + (lane >> 4) * 16) ^ ((lane & 7) << 4));

  const unsigned short* Ap = Inter + (long)(bm * 256) * FFN;
  const unsigned short* Bp = W2t + (long)(bn * 256) * FFN;

  f32x4 acc[8][4] = {};

  auto STAGE = [&](int kind, int h, int buf, int t) {
    const unsigned short* src = (kind ? Bp : Ap) + (long)(h * 128 + sr) * FFN + t * 64 + (scb >> 1);
    unsigned short* dst = sh + buf * 32768 + kind * 16384 + h * 8192 + tid * 8;
    __builtin_amdgcn_global_load_lds((gbl_void_t*)src, (lds_void_t*)dst, 16, 0, 0);
    __builtin_amdgcn_global_load_lds((gbl_void_t*)(src + 64L * FFN), (lds_void_t*)(dst + 4096), 16, 0, 0);
  };
  auto LDA8 = [&](bf16x8* a, int buf, int cb) {
    const char* base = (const char*)sh + buf * 65536 + wm * 16384 + l15 * 128 + cb;
#pragma unroll
    for (int m = 0; m < 8; ++m) a[m] = *(const bf16x8*)(base + m * 2048);
  };
  auto LDB2 = [&](bf16x8* b, int buf, int cb, int np) {
    const char* base = (const char*)sh + buf * 65536 + 32768 + (wn >> 1) * 16384 +
                       ((wn & 1) * 64 + l15) * 128 + cb;
    b[2 * np]     = *(const bf16x8*)(base + (2 * np) * 2048);
    b[2 * np + 1] = *(const bf16x8*)(base + (2 * np + 1) * 2048);
  };

  STAGE(0, 0, 0, 0); STAGE(0, 1, 0, 0); STAGE(1, 0, 0, 0); STAGE(1, 1, 0, 0);

  bf16x8 a[8], b[4];
  const int NT = FFN / 64;  // 224
  for (int t = 0; t < NT; ++t) {
    const int cur = t & 1, nxt = cur ^ 1;
    const bool pre = (t + 1 < NT);
    // P0: prefetch B(t+1); gate vmcnt(4); MFMA n01 kk0
    if (pre) { STAGE(1, 0, nxt, t + 1); STAGE(1, 1, nxt, t + 1);
               asm volatile("s_waitcnt vmcnt(4)" ::: "memory"); }
    else     { asm volatile("s_waitcnt vmcnt(0)" ::: "memory"); }
    SBAR();
    LDA8(a, cur, cb0); LDB2(b, cur, cb0, 0);
    __builtin_amdgcn_s_setprio(1);
#pragma unroll
    for (int m = 0; m < 8; ++m) {
      acc[m][0] = MFMA16(a[m], b[0], acc[m][0]);
      acc[m][1] = MFMA16(a[m], b[1], acc[m][1]);
    }
    __builtin_amdgcn_s_setprio(0);
    SBAR();
    // P1: prefetch A(t+1); MFMA n23 kk0
    if (pre) { STAGE(0, 0, nxt, t + 1); STAGE(0, 1, nxt, t + 1); }
    LDB2(b, cur, cb0, 1);
    __builtin_amdgcn_s_setprio(1);
#pragma unroll
    for (int m = 0; m < 8; ++m) {
      acc[m][2] = MFMA16(a[m], b[2], acc[m][2]);
      acc[m][3] = MFMA16(a[m], b[3], acc[m][3]);
    }
    __builtin_amdgcn_s_setprio(0);
    SBAR();
    // P2: MFMA n01 kk1
    LDA8(a, cur, cb1); LDB2(b, cur, cb1, 0);
    __builtin_amdgcn_s_setprio(1);
#pragma unroll
    for (int m = 0; m < 8; ++m) {
      acc[m][0] = MFMA16(a[m], b[0], acc[m][0]);
      acc[m][1] = MFMA16(a[m], b[1], acc[m][1]);
    }
    __builtin_amdgcn_s_setprio(0);
    SBAR();
    // P3: MFMA n23 kk1
    LDB2(b, cur, cb1, 1);
    __builtin_amdgcn_s_setprio(1);
#pragma unroll
    for (int m = 0; m < 8; ++m) {
      acc[m][2] = MFMA16(a[m], b[2], acc[m][2]);
      acc[m][3] = MFMA16(a[m], b[3], acc[m][3]);
    }
    __builtin_amdgcn_s_setprio(0);
    SBAR();
  }
  const int r0 = (lane >> 4) * 4;
#pragma unroll
  for (int m = 0; m < 8; ++m)
#pragma unroll
    for (int n = 0; n < 4; ++n)
#pragma unroll
      for (int r = 0; r < 4; ++r) {
        const int row = bm * 256 + wm * 128 + m * 16 + r0 + r;
        const int col = bn * 256 + wn * 64 + n * 16 + l15;
        Out[(long)row * HIDDEN + col] = acc[m][n][r];
      }
}

// ---- fallback down (round-2 verified) when ws lacks w2t space ----
__device__ __forceinline__ void stage_tile_128(const unsigned short* __restrict__ g, long ldk,
                                               unsigned short* lds, int wave, int lane) {
#pragma unroll
  for (int it = 0; it < 2; ++it) {
    const int row = (it * 4 + wave) * 16 + (lane >> 2);
    const int kcol = (lane & 3) * 8;
    const unsigned short* src = g + (long)row * ldk + kcol;
    unsigned short* dst = lds + row * 32 + kcol;
    __builtin_amdgcn_global_load_lds((gbl_void_t*)src, (lds_void_t*)dst, 16, 0, 0);
  }
}

__global__ __launch_bounds__(256, 2)
void down_nt_kernel(const unsigned short* __restrict__ Inter,
                    const float* __restrict__ W2,
                    float* __restrict__ Out) {
  __shared__ unsigned short As[128 * 32];
  __shared__ unsigned short Bs[128 * 32];
  const int t = threadIdx.x;
  const int lane = t & 63;
  const int wave = t >> 6;
  const int bm = blockIdx.x & 31;
  const int bn = blockIdx.x >> 5;
  const int wm = (wave >> 1) * 64;
  const int wn = (wave & 1) * 64;
  const unsigned short* gA = Inter + (long)(bm * 128) * FFN;

  f32x4 acc[4][4] = {};
  const int fr = lane & 15;
  const int kg = (lane >> 4) * 8;
  const int p = lane & 15;
  const int h0 = wave * 32 + (lane >> 4) * 8;
  const float* gB = W2 + bn * 128 + h0;

  for (int kt = 0; kt < FFN; kt += 32) {
    __syncthreads();
    stage_tile_128(gA + kt, FFN, As, wave, lane);
    const float* r0p = gB + (long)(kt + 2 * p) * HIDDEN;
    const float* r1p = r0p + HIDDEN;
    const float4 a0 = *reinterpret_cast<const float4*>(r0p);
    const float4 a1 = *reinterpret_cast<const float4*>(r0p + 4);
    const float4 b0 = *reinterpret_cast<const float4*>(r1p);
    const float4 b1 = *reinterpret_cast<const float4*>(r1p + 4);
    unsigned short lo[8], hi[8];
    lo[0] = f2b(a0.x); lo[1] = f2b(a0.y); lo[2] = f2b(a0.z); lo[3] = f2b(a0.w);
    lo[4] = f2b(a1.x); lo[5] = f2b(a1.y); lo[6] = f2b(a1.z); lo[7] = f2b(a1.w);
    hi[0] = f2b(b0.x); hi[1] = f2b(b0.y); hi[2] = f2b(b0.z); hi[3] = f2b(b0.w);
    hi[4] = f2b(b1.x); hi[5] = f2b(b1.y); hi[6] = f2b(b1.z); hi[7] = f2b(b1.w);
#pragma unroll
    for (int j = 0; j < 8; ++j) {
      const unsigned int pack = (unsigned int)lo[j] | ((unsigned int)hi[j] << 16);
      *reinterpret_cast<unsigned int*>(&Bs[(h0 + j) * 32 + 2 * p]) = pack;
    }
    __syncthreads();
    bf16x8 a[4], b[4];
#pragma unroll
    for (int m = 0; m < 4; ++m)
      a[m] = *reinterpret_cast<const bf16x8*>(&As[(wm + m * 16 + fr) * 32 + kg]);
#pragma unroll
    for (int n = 0; n < 4; ++n)
      b[n] = *reinterpret_cast<const bf16x8*>(&Bs[(wn + n * 16 + fr) * 32 + kg]);
#pragma unroll
    for (int m = 0; m < 4; ++m)
#pragma unroll
      for (int n = 0; n < 4; ++n)
        acc[m][n] = MFMA16(a[m], b[n], acc[m][n]);
  }
  const int r0 = (lane >> 4) * 4;
#pragma unroll
  for (int m = 0; m < 4; ++m)
#pragma unroll
    for (int n = 0; n < 4; ++n)
#pragma unroll
      for (int r = 0; r < 4; ++r) {
        const int row = bm * 128 + wm + m * 16 + r0 + r;
        const int col = bn * 128 + wn + n * 16 + fr;
        Out[(long)row * HIDDEN + col] = acc[m][n][r];
      }
}

extern "C" void kernel_launch(void* const* d_in, const int* in_sizes, int n_in,
                              void* d_out, int out_size, void* d_ws, size_t ws_size,
                              hipStream_t stream) {
  const float* x  = (const float*)d_in[0];
  const float* w1 = (const float*)d_in[1];
  const float* v1 = (const float*)d_in[2];
  const float* w2 = (const float*)d_in[3];
  float* out = (float*)d_out;

  // ws layout (bytes): xb 33,554,432 | w1b 117,440,512 | v1b 117,440,512 |
  //                    inter 117,440,512 | w2t 117,440,512  -> 503,316,480 total.
  const size_t REQ_SMALL = 385875968UL;
  const size_t REQ_FULL  = 503316480UL;
  if (ws_size < REQ_SMALL) return;
  const bool full = (ws_size >= REQ_FULL);
  char* ws = (char*)d_ws;
  unsigned short* xb     = (unsigned short*)(ws);
  unsigned short* w1b    = (unsigned short*)(ws + 33554432L);
  unsigned short* v1b    = (unsigned short*)(ws + 150994944L);
  unsigned short* interb = (unsigned short*)(ws + 268435456L);
  unsigned short* w2tb   = (unsigned short*)(ws + 385875968L);

  // half-split: F-rows [0, 8192) = j 0..3 ; F-rows [8192, 14336) = j 4..6
  const long HALF1 = 8192L * HIDDEN;                 // elements
  const long HALF2 = (long)(FFN - 8192) * HIDDEN;

  hipLaunchKernelGGL(cvt_kernel, dim3(2048), dim3(256), 0, stream, x, xb, (long)TOKENS * HIDDEN);
  // --- half 1: convert weights then immediately consume them (L3-hot) ---
  hipLaunchKernelGGL(cvt_kernel, dim3(2048), dim3(256), 0, stream, w1, w1b, HALF1);
  hipLaunchKernelGGL(cvt_kernel, dim3(2048), dim3(256), 0, stream, v1, v1b, HALF1);
  hipLaunchKernelGGL(gateup256p_kernel, dim3(256), dim3(512), 0, stream,
                     xb, w1b, v1b, interb, 0, 4);
  // --- half 2 ---
  hipLaunchKernelGGL(cvt_kernel, dim3(2048), dim3(256), 0, stream, w1 + HALF1, w1b + HALF1, HALF2);
  hipLaunchKernelGGL(cvt_kernel, dim3(2048), dim3(256), 0, stream, v1 + HALF1, v1b + HALF1, HALF2);
  hipLaunchKernelGGL(gateup256p_kernel, dim3(256), dim3(512), 0, stream,
                     xb, w1b, v1b, interb, 4, 7);

  if (full) {
    hipLaunchKernelGGL(transpose_cvt_kernel, dim3(FFN / 64, HIDDEN / 64), dim3(256), 0, stream, w2, w2tb);
    hipLaunchKernelGGL(down256_kernel, dim3((TOKENS / 256) * (HIDDEN / 256)), dim3(512), 0, stream,
                       interb, w2tb, out);
  } else {
    hipLaunchKernelGGL(down_nt_kernel, dim3((TOKENS / 128) * (HIDDEN / 128)), dim3(256), 0, stream,
                       interb, w2, out);
  }
}

// Round 16
// 1368.527 us; speedup vs baseline: 1.1716x; 1.0194x over previous
//
#include <hip/hip_runtime.h>
#include <hip/hip_bf16.h>
#include <stdint.h>

// DbrxExpertGLU: down = (silu(x@w1^T) * (x@v1^T)) @ w2
// T=4096, H=4096, F=14336. fp32 in/out; bf16 MFMA compute.
// R16: collapse 8 barriers/K-tile -> 1. All ds_reads issue in one region per
// tile (compiler emits fine-grained lgkmcnt); staging fully post-barrier.
// gateup: A-dbuf + WV-tribuf (160KB). down: A-dbuf + B-tribuf (160KB).
// Ledger/tile: issue A(t+1) then WV|B(t+2); gate vmcnt(4); lgkmcnt(0)+barrier.
#define TOKENS 4096
#define HIDDEN 4096
#define FFN    14336

typedef __attribute__((ext_vector_type(8))) short bf16x8;
typedef __attribute__((ext_vector_type(4))) float f32x4;
typedef __attribute__((ext_vector_type(8))) unsigned short u16x8;

typedef __attribute__((address_space(3))) void lds_void_t;
typedef const __attribute__((address_space(1))) void gbl_void_t;

static __device__ __forceinline__ unsigned short f2b(float f) {
  union { float f; unsigned int u; } v; v.f = f;
  unsigned int u = v.u;
  return (unsigned short)((u + 0x7FFFu + ((u >> 16) & 1u)) >> 16);  // RNE
}

// ---------------- fp32 -> bf16 convert ----------------
__global__ void cvt_kernel(const float* __restrict__ in, unsigned short* __restrict__ out, long n) {
  long idx = (long)blockIdx.x * blockDim.x + threadIdx.x;
  long stride = (long)gridDim.x * blockDim.x;
  for (long i = idx * 4; i < n; i += stride * 4) {
    const float4 v = *reinterpret_cast<const float4*>(in + i);
    ushort4 o;
    o.x = f2b(v.x); o.y = f2b(v.y); o.z = f2b(v.z); o.w = f2b(v.w);
    *reinterpret_cast<ushort4*>(out + i) = o;
  }
}

// ------- w2 [F][H] fp32 -> w2t [H][F] bf16 -------
__global__ void transpose_cvt_kernel(const float* __restrict__ in, unsigned short* __restrict__ out) {
  __shared__ float tile[64][65];
  const int f0 = blockIdx.x * 64;
  const int h0 = blockIdx.y * 64;
  const int t = threadIdx.x;
  const int rcol = (t & 15) * 4;
  const int rrow = t >> 4;
#pragma unroll
  for (int it = 0; it < 4; ++it) {
    int r = rrow + it * 16;
    const float4 v = *reinterpret_cast<const float4*>(in + (long)(f0 + r) * HIDDEN + h0 + rcol);
    tile[r][rcol] = v.x; tile[r][rcol + 1] = v.y; tile[r][rcol + 2] = v.z; tile[r][rcol + 3] = v.w;
  }
  __syncthreads();
  const int wrow = t >> 2;
  const int wc = (t & 3) * 16;
  u16x8 lo, hi;
#pragma unroll
  for (int j = 0; j < 8; ++j) lo[j] = f2b(tile[wc + j][wrow]);
#pragma unroll
  for (int j = 0; j < 8; ++j) hi[j] = f2b(tile[wc + 8 + j][wrow]);
  u16x8* dst = reinterpret_cast<u16x8*>(out + (long)(h0 + wrow) * FFN + f0 + wc);
  dst[0] = lo; dst[1] = hi;
}

#define MFMA16(a, b, c) __builtin_amdgcn_mfma_f32_16x16x32_bf16((a), (b), (c), 0, 0, 0)
#define SBAR()  __builtin_amdgcn_s_barrier()

static __device__ __forceinline__ int xcd_chunk(int bid, int nwg) {
  return (bid & 7) * (nwg >> 3) + (bid >> 3);
}

// ============ persistent fused gate/up: grid 256, F-tiles j0..j1, 1 barrier/tile ============
// LDS 160KB: A dbuf 2x32KB @0 | WV tribuf 3x32KB (W16K+V16K) @64KB.
__global__ __launch_bounds__(512, 2)
void gateup256p_kernel(const unsigned short* __restrict__ X,
                       const unsigned short* __restrict__ W1,
                       const unsigned short* __restrict__ V1,
                       unsigned short* __restrict__ Inter,
                       int j0, int j1) {
  __shared__ unsigned short sh[81920];  // 160 KB
  const int tid = threadIdx.x, lane = tid & 63, wid = tid >> 6;
  const int wm = wid >> 2, wn = wid & 3;
  const int p = blockIdx.x;           // 0..255, one block per CU
  const int bm = p & 15;              // T-tile (fixed per block)
  const int bnl = p >> 4;             // bn lane 0..15
  const int sr = tid >> 3;
  const int scb = (((tid & 7) ^ (sr & 7)) << 4);
  const int l15 = lane & 15;
  const int cb0 = (((lane >> 4) * 16) ^ ((lane & 7) << 4));
  const int cb1 = ((64 + (lane >> 4) * 16) ^ ((lane & 7) << 4));

  const unsigned short* Ap = X + (long)(bm * 256) * HIDDEN;

  auto LDA8 = [&](bf16x8* a, int bufA, int cb) {
    const char* base = (const char*)sh + bufA * 32768 + wm * 16384 + l15 * 128 + cb;
#pragma unroll
    for (int m = 0; m < 8; ++m) a[m] = *(const bf16x8*)(base + m * 2048);
  };
  auto LDW2 = [&](bf16x8* w, int b3, int cb) {
    const char* base = (const char*)sh + 65536 + b3 * 32768 + (wn * 32 + l15) * 128 + cb;
    w[0] = *(const bf16x8*)(base);
    w[1] = *(const bf16x8*)(base + 2048);
  };
  auto LDV2 = [&](bf16x8* v, int b3, int cb) {
    const char* base = (const char*)sh + 65536 + b3 * 32768 + 16384 + (wn * 32 + l15) * 128 + cb;
    v[0] = *(const bf16x8*)(base);
    v[1] = *(const bf16x8*)(base + 2048);
  };

  for (int j = j0; j < j1; ++j) {
    const int bn = j * 16 + bnl;
    const unsigned short* Wp = W1 + (long)(bn * 128) * HIDDEN;
    const unsigned short* Vp = V1 + (long)(bn * 128) * HIDDEN;

    auto STA = [&](int u, int bufA, int t) {   // A unit u: 64 rows, 8KB
      const unsigned short* src = Ap + (long)(u * 64 + sr) * HIDDEN + t * 64 + (scb >> 1);
      unsigned short* dst = sh + bufA * 16384 + u * 4096 + tid * 8;
      __builtin_amdgcn_global_load_lds((gbl_void_t*)src, (lds_void_t*)dst, 16, 0, 0);
    };
    auto STW = [&](int u, int b3, int t) {
      const unsigned short* src = Wp + (long)(u * 64 + sr) * HIDDEN + t * 64 + (scb >> 1);
      unsigned short* dst = sh + 32768 + b3 * 16384 + u * 4096 + tid * 8;
      __builtin_amdgcn_global_load_lds((gbl_void_t*)src, (lds_void_t*)dst, 16, 0, 0);
    };
    auto STV = [&](int u, int b3, int t) {
      const unsigned short* src = Vp + (long)(u * 64 + sr) * HIDDEN + t * 64 + (scb >> 1);
      unsigned short* dst = sh + 32768 + b3 * 16384 + 8192 + u * 4096 + tid * 8;
      __builtin_amdgcn_global_load_lds((gbl_void_t*)src, (lds_void_t*)dst, 16, 0, 0);
    };

    f32x4 accg[8][2] = {};
    f32x4 accu[8][2] = {};

    // prologue (issue order matters for ledger): WV(0)->slot0; A(0)->buf0; WV(1)->slot1
    STW(0, 0, 0); STW(1, 0, 0); STV(0, 0, 0); STV(1, 0, 0);
    STA(0, 0, 0); STA(1, 0, 0); STA(2, 0, 0); STA(3, 0, 0);
    STW(0, 1, 1); STW(1, 1, 1); STV(0, 1, 1); STV(1, 1, 1);

    bf16x8 a[8], w[2], v[2];
    const int NT = HIDDEN / 64;  // 64
    for (int t = 0; t < NT; ++t) {
      const int curA = t & 1, nxtA = curA ^ 1;
      const int b3 = t % 3, b3w = (t + 2) % 3;
      // own ds_reads of tile t-1 complete (consumed by MFMAs; cheap)
      asm volatile("s_waitcnt lgkmcnt(0)" ::: "memory");
      // gate: keep only newest 4 (WV(t+1)); drains A(t), WV(t)
      if (t + 1 < NT) { asm volatile("s_waitcnt vmcnt(4)" ::: "memory"); }
      else            { asm volatile("s_waitcnt vmcnt(0)" ::: "memory"); }
      SBAR();  // single barrier per tile
      // post-barrier staging (WAR-safe): A(t+1) FIRST, then WV(t+2) (ledger order)
      if (t + 1 < NT) { STA(0, nxtA, t + 1); STA(1, nxtA, t + 1);
                        STA(2, nxtA, t + 1); STA(3, nxtA, t + 1); }
      if (t + 2 < NT) { STW(0, b3w, t + 2); STW(1, b3w, t + 2);
                        STV(0, b3w, t + 2); STV(1, b3w, t + 2); }
      // kk0 reads + MFMA (compiler inserts fine-grained lgkmcnt)
      LDA8(a, curA, cb0); LDW2(w, b3, cb0); LDV2(v, b3, cb0);
      __builtin_amdgcn_s_setprio(1);
#pragma unroll
      for (int m = 0; m < 8; ++m) {
        accg[m][0] = MFMA16(a[m], w[0], accg[m][0]);
        accg[m][1] = MFMA16(a[m], w[1], accg[m][1]);
      }
#pragma unroll
      for (int m = 0; m < 8; ++m) {
        accu[m][0] = MFMA16(a[m], v[0], accu[m][0]);
        accu[m][1] = MFMA16(a[m], v[1], accu[m][1]);
      }
      __builtin_amdgcn_s_setprio(0);
      // kk1 reads + MFMA
      LDA8(a, curA, cb1); LDW2(w, b3, cb1); LDV2(v, b3, cb1);
      __builtin_amdgcn_s_setprio(1);
#pragma unroll
      for (int m = 0; m < 8; ++m) {
        accg[m][0] = MFMA16(a[m], w[0], accg[m][0]);
        accg[m][1] = MFMA16(a[m], w[1], accg[m][1]);
      }
#pragma unroll
      for (int m = 0; m < 8; ++m) {
        accu[m][0] = MFMA16(a[m], v[0], accu[m][0]);
        accu[m][1] = MFMA16(a[m], v[1], accu[m][1]);
      }
      __builtin_amdgcn_s_setprio(0);
    }
    // epilogue: silu(g)*u -> bf16. C/D map: col=lane&15, row=(lane>>4)*4+r (m89)
    const int r0 = (lane >> 4) * 4;
#pragma unroll
    for (int m = 0; m < 8; ++m)
#pragma unroll
      for (int n = 0; n < 2; ++n)
#pragma unroll
        for (int r = 0; r < 4; ++r) {
          const float g = accg[m][n][r];
          const float u = accu[m][n][r];
          const float s = g / (1.0f + __expf(-g));
          const int row = bm * 256 + wm * 128 + m * 16 + r0 + r;
          const int col = bn * 128 + wn * 32 + n * 16 + l15;
          Inter[(long)row * FFN + col] = f2b(s * u);
        }
    // drain epilogue stores so the next group's vmcnt ledger starts clean
    asm volatile("s_waitcnt vmcnt(0)" ::: "memory");
  }
}

// ============ down GEMM-BT: 256x256, BK=64, 8 waves, 1 barrier/tile ============
// LDS 160KB: A dbuf 2x32KB @0 | B tribuf 3x32KB @64KB.
__global__ __launch_bounds__(512, 2)
void down256_kernel(const unsigned short* __restrict__ Inter,
                    const unsigned short* __restrict__ W2t,
                    float* __restrict__ Out) {
  __shared__ unsigned short sh[81920];  // 160 KB
  const int tid = threadIdx.x, lane = tid & 63, wid = tid >> 6;
  const int wm = wid >> 2, wn = wid & 3;
  const int swz = xcd_chunk(blockIdx.x, (TOKENS / 256) * (HIDDEN / 256));  // 256
  const int bm = swz & 15;
  const int bn = swz >> 4;
  const int sr = tid >> 3;
  const int scb = (((tid & 7) ^ (sr & 7)) << 4);
  const int l15 = lane & 15;
  const int cb0 = (((lane >> 4) * 16) ^ ((lane & 7) << 4));
  const int cb1 = ((64 + (lane >> 4) * 16) ^ ((lane & 7) << 4));

  const unsigned short* Ap = Inter + (long)(bm * 256) * FFN;
  const unsigned short* Bp = W2t + (long)(bn * 256) * FFN;

  f32x4 acc[8][4] = {};

  auto STA = [&](int h, int bufA, int t) {   // A half h: 128 rows, 2 gloads
    const unsigned short* src = Ap + (long)(h * 128 + sr) * FFN + t * 64 + (scb >> 1);
    unsigned short* dst = sh + bufA * 16384 + h * 8192 + tid * 8;
    __builtin_amdgcn_global_load_lds((gbl_void_t*)src, (lds_void_t*)dst, 16, 0, 0);
    __builtin_amdgcn_global_load_lds((gbl_void_t*)(src + 64L * FFN), (lds_void_t*)(dst + 4096), 16, 0, 0);
  };
  auto STB = [&](int h, int s3, int t) {     // B half h into tri-slot s3
    const unsigned short* src = Bp + (long)(h * 128 + sr) * FFN + t * 64 + (scb >> 1);
    unsigned short* dst = sh + 32768 + s3 * 16384 + h * 8192 + tid * 8;
    __builtin_amdgcn_global_load_lds((gbl_void_t*)src, (lds_void_t*)dst, 16, 0, 0);
    __builtin_amdgcn_global_load_lds((gbl_void_t*)(src + 64L * FFN), (lds_void_t*)(dst + 4096), 16, 0, 0);
  };
  auto LDA8 = [&](bf16x8* a, int bufA, int cb) {
    const char* base = (const char*)sh + bufA * 32768 + wm * 16384 + l15 * 128 + cb;
#pragma unroll
    for (int m = 0; m < 8; ++m) a[m] = *(const bf16x8*)(base + m * 2048);
  };
  auto LDB2 = [&](bf16x8* b, int s3, int cb, int np) {
    const char* base = (const char*)sh + 65536 + s3 * 32768 + (wn >> 1) * 16384 +
                       ((wn & 1) * 64 + l15) * 128 + cb;
    b[2 * np]     = *(const bf16x8*)(base + (2 * np) * 2048);
    b[2 * np + 1] = *(const bf16x8*)(base + (2 * np + 1) * 2048);
  };

  // prologue (ledger order): B(0)->s0; A(0)->buf0; B(1)->s1
  STB(0, 0, 0); STB(1, 0, 0);
  STA(0, 0, 0); STA(1, 0, 0);
  STB(0, 1, 1); STB(1, 1, 1);

  bf16x8 a[8], b[4];
  const int NT = FFN / 64;  // 224
  for (int t = 0; t < NT; ++t) {
    const int curA = t & 1, nxtA = curA ^ 1;
    const int b3 = t % 3, b3w = (t + 2) % 3;
    asm volatile("s_waitcnt lgkmcnt(0)" ::: "memory");
    // gate: keep only newest 4 (B(t+1)); drains A(t), B(t)
    if (t + 1 < NT) { asm volatile("s_waitcnt vmcnt(4)" ::: "memory"); }
    else            { asm volatile("s_waitcnt vmcnt(0)" ::: "memory"); }
    SBAR();
    // post-barrier staging: A(t+1) FIRST, then B(t+2)
    if (t + 1 < NT) { STA(0, nxtA, t + 1); STA(1, nxtA, t + 1); }
    if (t + 2 < NT) { STB(0, b3w, t + 2); STB(1, b3w, t + 2); }
    // kk0
    LDA8(a, curA, cb0); LDB2(b, b3, cb0, 0); LDB2(b, b3, cb0, 1);
    __builtin_amdgcn_s_setprio(1);
#pragma unroll
    for (int m = 0; m < 8; ++m) {
      acc[m][0] = MFMA16(a[m], b[0], acc[m][0]);
      acc[m][1] = MFMA16(a[m], b[1], acc[m][1]);
    }
#pragma unroll
    for (int m = 0; m < 8; ++m) {
      acc[m][2] = MFMA16(a[m], b[2], acc[m][2]);
      acc[m][3] = MFMA16(a[m], b[3], acc[m][3]);
    }
    __builtin_amdgcn_s_setprio(0);
    // kk1
    LDA8(a, curA, cb1); LDB2(b, b3, cb1, 0); LDB2(b, b3, cb1, 1);
    __builtin_amdgcn_s_setprio(1);
#pragma unroll
    for (int m = 0; m < 8; ++m) {
      acc[m][0] = MFMA16(a[m], b[0], acc[m][0]);
      acc[m][1] = MFMA16(a[m], b[1], acc[m][1]);
    }
#pragma unroll
    for (int m = 0; m < 8; ++m) {
      acc[m][2] = MFMA16(a[m], b[2], acc[m][2]);
      acc[m][3] = MFMA16(a[m], b[3], acc[m][3]);
    }
    __builtin_amdgcn_s_setprio(0);
  }
  const int r0 = (lane >> 4) * 4;
#pragma unroll
  for (int m = 0; m < 8; ++m)
#pragma unroll
    for (int n = 0; n < 4; ++n)
#pragma unroll
      for (int r = 0; r < 4; ++r) {
        const int row = bm * 256 + wm * 128 + m * 16 + r0 + r;
        const int col = bn * 256 + wn * 64 + n * 16 + l15;
        Out[(long)row * HIDDEN + col] = acc[m][n][r];
      }
}

// ---- fallback down (round-2 verified) when ws lacks w2t space ----
__device__ __forceinline__ void stage_tile_128(const unsigned short* __restrict__ g, long ldk,
                                               unsigned short* lds, int wave, int lane) {
#pragma unroll
  for (int it = 0; it < 2; ++it) {
    const int row = (it * 4 + wave) * 16 + (lane >> 2);
    const int kcol = (lane & 3) * 8;
    const unsigned short* src = g + (long)row * ldk + kcol;
    unsigned short* dst = lds + row * 32 + kcol;
    __builtin_amdgcn_global_load_lds((gbl_void_t*)src, (lds_void_t*)dst, 16, 0, 0);
  }
}

__global__ __launch_bounds__(256, 2)
void down_nt_kernel(const unsigned short* __restrict__ Inter,
                    const float* __restrict__ W2,
                    float* __restrict__ Out) {
  __shared__ unsigned short As[128 * 32];
  __shared__ unsigned short Bs[128 * 32];
  const int t = threadIdx.x;
  const int lane = t & 63;
  const int wave = t >> 6;
  const int bm = blockIdx.x & 31;
  const int bn = blockIdx.x >> 5;
  const int wm = (wave >> 1) * 64;
  const int wn = (wave & 1) * 64;
  const unsigned short* gA = Inter + (long)(bm * 128) * FFN;

  f32x4 acc[4][4] = {};
  const int fr = lane & 15;
  const int kg = (lane >> 4) * 8;
  const int p = lane & 15;
  const int h0 = wave * 32 + (lane >> 4) * 8;
  const float* gB = W2 + bn * 128 + h0;

  for (int kt = 0; kt < FFN; kt += 32) {
    __syncthreads();
    stage_tile_128(gA + kt, FFN, As, wave, lane);
    const float* r0p = gB + (long)(kt + 2 * p) * HIDDEN;
    const float* r1p = r0p + HIDDEN;
    const float4 a0 = *reinterpret_cast<const float4*>(r0p);
    const float4 a1 = *reinterpret_cast<const float4*>(r0p + 4);
    const float4 b0 = *reinterpret_cast<const float4*>(r1p);
    const float4 b1 = *reinterpret_cast<const float4*>(r1p + 4);
    unsigned short lo[8], hi[8];
    lo[0] = f2b(a0.x); lo[1] = f2b(a0.y); lo[2] = f2b(a0.z); lo[3] = f2b(a0.w);
    lo[4] = f2b(a1.x); lo[5] = f2b(a1.y); lo[6] = f2b(a1.z); lo[7] = f2b(a1.w);
    hi[0] = f2b(b0.x); hi[1] = f2b(b0.y); hi[2] = f2b(b0.z); hi[3] = f2b(b0.w);
    hi[4] = f2b(b1.x); hi[5] = f2b(b1.y); hi[6] = f2b(b1.z); hi[7] = f2b(b1.w);
#pragma unroll
    for (int j = 0; j < 8; ++j) {
      const unsigned int pack = (unsigned int)lo[j] | ((unsigned int)hi[j] << 16);
      *reinterpret_cast<unsigned int*>(&Bs[(h0 + j) * 32 + 2 * p]) = pack;
    }
    __syncthreads();
    bf16x8 a[4], b[4];
#pragma unroll
    for (int m = 0; m < 4; ++m)
      a[m] = *reinterpret_cast<const bf16x8*>(&As[(wm + m * 16 + fr) * 32 + kg]);
#pragma unroll
    for (int n = 0; n < 4; ++n)
      b[n] = *reinterpret_cast<const bf16x8*>(&Bs[(wn + n * 16 + fr) * 32 + kg]);
#pragma unroll
    for (int m = 0; m < 4; ++m)
#pragma unroll
      for (int n = 0; n < 4; ++n)
        acc[m][n] = MFMA16(a[m], b[n], acc[m][n]);
  }
  const int r0 = (lane >> 4) * 4;
#pragma unroll
  for (int m = 0; m < 4; ++m)
#pragma unroll
    for (int n = 0; n < 4; ++n)
#pragma unroll
      for (int r = 0; r < 4; ++r) {
        const int row = bm * 128 + wm + m * 16 + r0 + r;
        const int col = bn * 128 + wn + n * 16 + fr;
        Out[(long)row * HIDDEN + col] = acc[m][n][r];
      }
}

extern "C" void kernel_launch(void* const* d_in, const int* in_sizes, int n_in,
                              void* d_out, int out_size, void* d_ws, size_t ws_size,
                              hipStream_t stream) {
  const float* x  = (const float*)d_in[0];
  const float* w1 = (const float*)d_in[1];
  const float* v1 = (const float*)d_in[2];
  const float* w2 = (const float*)d_in[3];
  float* out = (float*)d_out;

  // ws layout (bytes): xb 33,554,432 | w1b 117,440,512 | v1b 117,440,512 |
  //                    inter 117,440,512 | w2t 117,440,512  -> 503,316,480 total.
  const size_t REQ_SMALL = 385875968UL;
  const size_t REQ_FULL  = 503316480UL;
  if (ws_size < REQ_SMALL) return;
  const bool full = (ws_size >= REQ_FULL);
  char* ws = (char*)d_ws;
  unsigned short* xb     = (unsigned short*)(ws);
  unsigned short* w1b    = (unsigned short*)(ws + 33554432L);
  unsigned short* v1b    = (unsigned short*)(ws + 150994944L);
  unsigned short* interb = (unsigned short*)(ws + 268435456L);
  unsigned short* w2tb   = (unsigned short*)(ws + 385875968L);

  // half-split: F-rows [0, 8192) = j 0..3 ; F-rows [8192, 14336) = j 4..6
  const long HALF1 = 8192L * HIDDEN;
  const long HALF2 = (long)(FFN - 8192) * HIDDEN;

  hipLaunchKernelGGL(cvt_kernel, dim3(2048), dim3(256), 0, stream, x, xb, (long)TOKENS * HIDDEN);
  hipLaunchKernelGGL(cvt_kernel, dim3(2048), dim3(256), 0, stream, w1, w1b, HALF1);
  hipLaunchKernelGGL(cvt_kernel, dim3(2048), dim3(256), 0, stream, v1, v1b, HALF1);
  hipLaunchKernelGGL(gateup256p_kernel, dim3(256), dim3(512), 0, stream,
                     xb, w1b, v1b, interb, 0, 4);
  hipLaunchKernelGGL(cvt_kernel, dim3(2048), dim3(256), 0, stream, w1 + HALF1, w1b + HALF1, HALF2);
  hipLaunchKernelGGL(cvt_kernel, dim3(2048), dim3(256), 0, stream, v1 + HALF1, v1b + HALF1, HALF2);
  hipLaunchKernelGGL(gateup256p_kernel, dim3(256), dim3(512), 0, stream,
                     xb, w1b, v1b, interb, 4, 7);

  if (full) {
    hipLaunchKernelGGL(transpose_cvt_kernel, dim3(FFN / 64, HIDDEN / 64), dim3(256), 0, stream, w2, w2tb);
    hipLaunchKernelGGL(down256_kernel, dim3((TOKENS / 256) * (HIDDEN / 256)), dim3(512), 0, stream,
                       interb, w2tb, out);
  } else {
    hipLaunchKernelGGL(down_nt_kernel, dim3((TOKENS / 128) * (HIDDEN / 128)), dim3(256), 0, stream,
                       interb, w2, out);
  }
}

// Round 17
// 1365.038 us; speedup vs baseline: 1.1746x; 1.0026x over previous
//
#include <hip/hip_runtime.h>
#include <hip/hip_bf16.h>
#include <stdint.h>

// DbrxExpertGLU: down = (silu(x@w1^T) * (x@v1^T)) @ w2
// T=4096, H=4096, F=14336. fp32 in/out; bf16 MFMA compute.
// R17 = R16 + register-level kstep hoisting: ALL 24 ds_reads of a K-tile issue
// up-front into disjoint register sets (kk0->a0/w0/v0, kk1->a1/w1/v1), then
// both MFMA clusters run. LDS pipe drains kk1 reads under kk0's MFMAs
// (within-wave MFMA || LDS overlap; pipes were measured ~serial: 4295cyc/tile
// vs LDS 2290 + MFMA 2480).
#define TOKENS 4096
#define HIDDEN 4096
#define FFN    14336

typedef __attribute__((ext_vector_type(8))) short bf16x8;
typedef __attribute__((ext_vector_type(4))) float f32x4;
typedef __attribute__((ext_vector_type(8))) unsigned short u16x8;

typedef __attribute__((address_space(3))) void lds_void_t;
typedef const __attribute__((address_space(1))) void gbl_void_t;

static __device__ __forceinline__ unsigned short f2b(float f) {
  union { float f; unsigned int u; } v; v.f = f;
  unsigned int u = v.u;
  return (unsigned short)((u + 0x7FFFu + ((u >> 16) & 1u)) >> 16);  // RNE
}

// ---------------- fp32 -> bf16 convert ----------------
__global__ void cvt_kernel(const float* __restrict__ in, unsigned short* __restrict__ out, long n) {
  long idx = (long)blockIdx.x * blockDim.x + threadIdx.x;
  long stride = (long)gridDim.x * blockDim.x;
  for (long i = idx * 4; i < n; i += stride * 4) {
    const float4 v = *reinterpret_cast<const float4*>(in + i);
    ushort4 o;
    o.x = f2b(v.x); o.y = f2b(v.y); o.z = f2b(v.z); o.w = f2b(v.w);
    *reinterpret_cast<ushort4*>(out + i) = o;
  }
}

// ------- w2 [F][H] fp32 -> w2t [H][F] bf16 -------
__global__ void transpose_cvt_kernel(const float* __restrict__ in, unsigned short* __restrict__ out) {
  __shared__ float tile[64][65];
  const int f0 = blockIdx.x * 64;
  const int h0 = blockIdx.y * 64;
  const int t = threadIdx.x;
  const int rcol = (t & 15) * 4;
  const int rrow = t >> 4;
#pragma unroll
  for (int it = 0; it < 4; ++it) {
    int r = rrow + it * 16;
    const float4 v = *reinterpret_cast<const float4*>(in + (long)(f0 + r) * HIDDEN + h0 + rcol);
    tile[r][rcol] = v.x; tile[r][rcol + 1] = v.y; tile[r][rcol + 2] = v.z; tile[r][rcol + 3] = v.w;
  }
  __syncthreads();
  const int wrow = t >> 2;
  const int wc = (t & 3) * 16;
  u16x8 lo, hi;
#pragma unroll
  for (int j = 0; j < 8; ++j) lo[j] = f2b(tile[wc + j][wrow]);
#pragma unroll
  for (int j = 0; j < 8; ++j) hi[j] = f2b(tile[wc + 8 + j][wrow]);
  u16x8* dst = reinterpret_cast<u16x8*>(out + (long)(h0 + wrow) * FFN + f0 + wc);
  dst[0] = lo; dst[1] = hi;
}

#define MFMA16(a, b, c) __builtin_amdgcn_mfma_f32_16x16x32_bf16((a), (b), (c), 0, 0, 0)
#define SBAR()  __builtin_amdgcn_s_barrier()

static __device__ __forceinline__ int xcd_chunk(int bid, int nwg) {
  return (bid & 7) * (nwg >> 3) + (bid >> 3);
}

// ============ persistent fused gate/up: grid 256, F-tiles j0..j1, 1 barrier/tile ============
// LDS 160KB: A dbuf 2x32KB @0 | WV tribuf 3x32KB (W16K+V16K) @64KB.
__global__ __launch_bounds__(512, 2)
void gateup256p_kernel(const unsigned short* __restrict__ X,
                       const unsigned short* __restrict__ W1,
                       const unsigned short* __restrict__ V1,
                       unsigned short* __restrict__ Inter,
                       int j0, int j1) {
  __shared__ unsigned short sh[81920];  // 160 KB
  const int tid = threadIdx.x, lane = tid & 63, wid = tid >> 6;
  const int wm = wid >> 2, wn = wid & 3;
  const int p = blockIdx.x;           // 0..255, one block per CU
  const int bm = p & 15;              // T-tile (fixed per block)
  const int bnl = p >> 4;             // bn lane 0..15
  const int sr = tid >> 3;
  const int scb = (((tid & 7) ^ (sr & 7)) << 4);
  const int l15 = lane & 15;
  const int cb0 = (((lane >> 4) * 16) ^ ((lane & 7) << 4));
  const int cb1 = ((64 + (lane >> 4) * 16) ^ ((lane & 7) << 4));

  const unsigned short* Ap = X + (long)(bm * 256) * HIDDEN;

  auto LDA8 = [&](bf16x8* a, int bufA, int cb) {
    const char* base = (const char*)sh + bufA * 32768 + wm * 16384 + l15 * 128 + cb;
#pragma unroll
    for (int m = 0; m < 8; ++m) a[m] = *(const bf16x8*)(base + m * 2048);
  };
  auto LDW2 = [&](bf16x8* w, int b3, int cb) {
    const char* base = (const char*)sh + 65536 + b3 * 32768 + (wn * 32 + l15) * 128 + cb;
    w[0] = *(const bf16x8*)(base);
    w[1] = *(const bf16x8*)(base + 2048);
  };
  auto LDV2 = [&](bf16x8* v, int b3, int cb) {
    const char* base = (const char*)sh + 65536 + b3 * 32768 + 16384 + (wn * 32 + l15) * 128 + cb;
    v[0] = *(const bf16x8*)(base);
    v[1] = *(const bf16x8*)(base + 2048);
  };

  for (int j = j0; j < j1; ++j) {
    const int bn = j * 16 + bnl;
    const unsigned short* Wp = W1 + (long)(bn * 128) * HIDDEN;
    const unsigned short* Vp = V1 + (long)(bn * 128) * HIDDEN;

    auto STA = [&](int u, int bufA, int t) {   // A unit u: 64 rows, 8KB
      const unsigned short* src = Ap + (long)(u * 64 + sr) * HIDDEN + t * 64 + (scb >> 1);
      unsigned short* dst = sh + bufA * 16384 + u * 4096 + tid * 8;
      __builtin_amdgcn_global_load_lds((gbl_void_t*)src, (lds_void_t*)dst, 16, 0, 0);
    };
    auto STW = [&](int u, int b3, int t) {
      const unsigned short* src = Wp + (long)(u * 64 + sr) * HIDDEN + t * 64 + (scb >> 1);
      unsigned short* dst = sh + 32768 + b3 * 16384 + u * 4096 + tid * 8;
      __builtin_amdgcn_global_load_lds((gbl_void_t*)src, (lds_void_t*)dst, 16, 0, 0);
    };
    auto STV = [&](int u, int b3, int t) {
      const unsigned short* src = Vp + (long)(u * 64 + sr) * HIDDEN + t * 64 + (scb >> 1);
      unsigned short* dst = sh + 32768 + b3 * 16384 + 8192 + u * 4096 + tid * 8;
      __builtin_amdgcn_global_load_lds((gbl_void_t*)src, (lds_void_t*)dst, 16, 0, 0);
    };

    f32x4 accg[8][2] = {};
    f32x4 accu[8][2] = {};

    // prologue (ledger order): WV(0)->slot0; A(0)->buf0; WV(1)->slot1
    STW(0, 0, 0); STW(1, 0, 0); STV(0, 0, 0); STV(1, 0, 0);
    STA(0, 0, 0); STA(1, 0, 0); STA(2, 0, 0); STA(3, 0, 0);
    STW(0, 1, 1); STW(1, 1, 1); STV(0, 1, 1); STV(1, 1, 1);

    bf16x8 a0[8], w0[2], v0[2];   // kk0 fragment set
    bf16x8 a1[8], w1[2], v1[2];   // kk1 fragment set
    const int NT = HIDDEN / 64;  // 64
    for (int t = 0; t < NT; ++t) {
      const int curA = t & 1, nxtA = curA ^ 1;
      const int b3 = t % 3, b3w = (t + 2) % 3;
      // own ds_reads of tile t-1 complete before crossing barrier (WAR safety)
      asm volatile("s_waitcnt lgkmcnt(0)" ::: "memory");
      // gate: keep only newest 4 (WV(t+1)); drains A(t), WV(t)
      if (t + 1 < NT) { asm volatile("s_waitcnt vmcnt(4)" ::: "memory"); }
      else            { asm volatile("s_waitcnt vmcnt(0)" ::: "memory"); }
      SBAR();  // single barrier per tile
      // post-barrier staging (ledger order): A(t+1) FIRST, then WV(t+2)
      if (t + 1 < NT) { STA(0, nxtA, t + 1); STA(1, nxtA, t + 1);
                        STA(2, nxtA, t + 1); STA(3, nxtA, t + 1); }
      if (t + 2 < NT) { STW(0, b3w, t + 2); STW(1, b3w, t + 2);
                        STV(0, b3w, t + 2); STV(1, b3w, t + 2); }
      // hoist ALL tile reads up front (both ksteps, disjoint reg sets)
      LDA8(a0, curA, cb0); LDW2(w0, b3, cb0); LDV2(v0, b3, cb0);
      LDA8(a1, curA, cb1); LDW2(w1, b3, cb1); LDV2(v1, b3, cb1);
      // kk0 MFMAs (compiler waits only kk0 reads; kk1 drains underneath)
      __builtin_amdgcn_s_setprio(1);
#pragma unroll
      for (int m = 0; m < 8; ++m) {
        accg[m][0] = MFMA16(a0[m], w0[0], accg[m][0]);
        accg[m][1] = MFMA16(a0[m], w0[1], accg[m][1]);
      }
#pragma unroll
      for (int m = 0; m < 8; ++m) {
        accu[m][0] = MFMA16(a0[m], v0[0], accu[m][0]);
        accu[m][1] = MFMA16(a0[m], v0[1], accu[m][1]);
      }
      // kk1 MFMAs
#pragma unroll
      for (int m = 0; m < 8; ++m) {
        accg[m][0] = MFMA16(a1[m], w1[0], accg[m][0]);
        accg[m][1] = MFMA16(a1[m], w1[1], accg[m][1]);
      }
#pragma unroll
      for (int m = 0; m < 8; ++m) {
        accu[m][0] = MFMA16(a1[m], v1[0], accu[m][0]);
        accu[m][1] = MFMA16(a1[m], v1[1], accu[m][1]);
      }
      __builtin_amdgcn_s_setprio(0);
    }
    // epilogue: silu(g)*u -> bf16. C/D map: col=lane&15, row=(lane>>4)*4+r (m89)
    const int r0 = (lane >> 4) * 4;
#pragma unroll
    for (int m = 0; m < 8; ++m)
#pragma unroll
      for (int n = 0; n < 2; ++n)
#pragma unroll
        for (int r = 0; r < 4; ++r) {
          const float g = accg[m][n][r];
          const float u = accu[m][n][r];
          const float s = g / (1.0f + __expf(-g));
          const int row = bm * 256 + wm * 128 + m * 16 + r0 + r;
          const int col = bn * 128 + wn * 32 + n * 16 + l15;
          Inter[(long)row * FFN + col] = f2b(s * u);
        }
    // drain epilogue stores so the next group's vmcnt ledger starts clean
    asm volatile("s_waitcnt vmcnt(0)" ::: "memory");
  }
}

// ============ down GEMM-BT: 256x256, BK=64, 8 waves, 1 barrier/tile ============
// LDS 160KB: A dbuf 2x32KB @0 | B tribuf 3x32KB @64KB.
__global__ __launch_bounds__(512, 2)
void down256_kernel(const unsigned short* __restrict__ Inter,
                    const unsigned short* __restrict__ W2t,
                    float* __restrict__ Out) {
  __shared__ unsigned short sh[81920];  // 160 KB
  const int tid = threadIdx.x, lane = tid & 63, wid = tid >> 6;
  const int wm = wid >> 2, wn = wid & 3;
  const int swz = xcd_chunk(blockIdx.x, (TOKENS / 256) * (HIDDEN / 256));  // 256
  const int bm = swz & 15;
  const int bn = swz >> 4;
  const int sr = tid >> 3;
  const int scb = (((tid & 7) ^ (sr & 7)) << 4);
  const int l15 = lane & 15;
  const int cb0 = (((lane >> 4) * 16) ^ ((lane & 7) << 4));
  const int cb1 = ((64 + (lane >> 4) * 16) ^ ((lane & 7) << 4));

  const unsigned short* Ap = Inter + (long)(bm * 256) * FFN;
  const unsigned short* Bp = W2t + (long)(bn * 256) * FFN;

  f32x4 acc[8][4] = {};

  auto STA = [&](int h, int bufA, int t) {   // A half h: 128 rows, 2 gloads
    const unsigned short* src = Ap + (long)(h * 128 + sr) * FFN + t * 64 + (scb >> 1);
    unsigned short* dst = sh + bufA * 16384 + h * 8192 + tid * 8;
    __builtin_amdgcn_global_load_lds((gbl_void_t*)src, (lds_void_t*)dst, 16, 0, 0);
    __builtin_amdgcn_global_load_lds((gbl_void_t*)(src + 64L * FFN), (lds_void_t*)(dst + 4096), 16, 0, 0);
  };
  auto STB = [&](int h, int s3, int t) {     // B half h into tri-slot s3
    const unsigned short* src = Bp + (long)(h * 128 + sr) * FFN + t * 64 + (scb >> 1);
    unsigned short* dst = sh + 32768 + s3 * 16384 + h * 8192 + tid * 8;
    __builtin_amdgcn_global_load_lds((gbl_void_t*)src, (lds_void_t*)dst, 16, 0, 0);
    __builtin_amdgcn_global_load_lds((gbl_void_t*)(src + 64L * FFN), (lds_void_t*)(dst + 4096), 16, 0, 0);
  };
  auto LDA8 = [&](bf16x8* a, int bufA, int cb) {
    const char* base = (const char*)sh + bufA * 32768 + wm * 16384 + l15 * 128 + cb;
#pragma unroll
    for (int m = 0; m < 8; ++m) a[m] = *(const bf16x8*)(base + m * 2048);
  };
  auto LDB4 = [&](bf16x8* b, int s3, int cb) {
    const char* base = (const char*)sh + 65536 + s3 * 32768 + (wn >> 1) * 16384 +
                       ((wn & 1) * 64 + l15) * 128 + cb;
#pragma unroll
    for (int n = 0; n < 4; ++n) b[n] = *(const bf16x8*)(base + n * 2048);
  };

  // prologue (ledger order): B(0)->s0; A(0)->buf0; B(1)->s1
  STB(0, 0, 0); STB(1, 0, 0);
  STA(0, 0, 0); STA(1, 0, 0);
  STB(0, 1, 1); STB(1, 1, 1);

  bf16x8 a0[8], b0[4];   // kk0
  bf16x8 a1[8], b1[4];   // kk1
  const int NT = FFN / 64;  // 224
  for (int t = 0; t < NT; ++t) {
    const int curA = t & 1, nxtA = curA ^ 1;
    const int b3 = t % 3, b3w = (t + 2) % 3;
    asm volatile("s_waitcnt lgkmcnt(0)" ::: "memory");
    if (t + 1 < NT) { asm volatile("s_waitcnt vmcnt(4)" ::: "memory"); }
    else            { asm volatile("s_waitcnt vmcnt(0)" ::: "memory"); }
    SBAR();
    if (t + 1 < NT) { STA(0, nxtA, t + 1); STA(1, nxtA, t + 1); }
    if (t + 2 < NT) { STB(0, b3w, t + 2); STB(1, b3w, t + 2); }
    // hoist all reads (both ksteps)
    LDA8(a0, curA, cb0); LDB4(b0, b3, cb0);
    LDA8(a1, curA, cb1); LDB4(b1, b3, cb1);
    __builtin_amdgcn_s_setprio(1);
#pragma unroll
    for (int m = 0; m < 8; ++m) {
      acc[m][0] = MFMA16(a0[m], b0[0], acc[m][0]);
      acc[m][1] = MFMA16(a0[m], b0[1], acc[m][1]);
    }
#pragma unroll
    for (int m = 0; m < 8; ++m) {
      acc[m][2] = MFMA16(a0[m], b0[2], acc[m][2]);
      acc[m][3] = MFMA16(a0[m], b0[3], acc[m][3]);
    }
#pragma unroll
    for (int m = 0; m < 8; ++m) {
      acc[m][0] = MFMA16(a1[m], b1[0], acc[m][0]);
      acc[m][1] = MFMA16(a1[m], b1[1], acc[m][1]);
    }
#pragma unroll
    for (int m = 0; m < 8; ++m) {
      acc[m][2] = MFMA16(a1[m], b1[2], acc[m][2]);
      acc[m][3] = MFMA16(a1[m], b1[3], acc[m][3]);
    }
    __builtin_amdgcn_s_setprio(0);
  }
  const int r0 = (lane >> 4) * 4;
#pragma unroll
  for (int m = 0; m < 8; ++m)
#pragma unroll
    for (int n = 0; n < 4; ++n)
#pragma unroll
      for (int r = 0; r < 4; ++r) {
        const int row = bm * 256 + wm * 128 + m * 16 + r0 + r;
        const int col = bn * 256 + wn * 64 + n * 16 + l15;
        Out[(long)row * HIDDEN + col] = acc[m][n][r];
      }
}

// ---- fallback down (round-2 verified) when ws lacks w2t space ----
__device__ __forceinline__ void stage_tile_128(const unsigned short* __restrict__ g, long ldk,
                                               unsigned short* lds, int wave, int lane) {
#pragma unroll
  for (int it = 0; it < 2; ++it) {
    const int row = (it * 4 + wave) * 16 + (lane >> 2);
    const int kcol = (lane & 3) * 8;
    const unsigned short* src = g + (long)row * ldk + kcol;
    unsigned short* dst = lds + row * 32 + kcol;
    __builtin_amdgcn_global_load_lds((gbl_void_t*)src, (lds_void_t*)dst, 16, 0, 0);
  }
}

__global__ __launch_bounds__(256, 2)
void down_nt_kernel(const unsigned short* __restrict__ Inter,
                    const float* __restrict__ W2,
                    float* __restrict__ Out) {
  __shared__ unsigned short As[128 * 32];
  __shared__ unsigned short Bs[128 * 32];
  const int t = threadIdx.x;
  const int lane = t & 63;
  const int wave = t >> 6;
  const int bm = blockIdx.x & 31;
  const int bn = blockIdx.x >> 5;
  const int wm = (wave >> 1) * 64;
  const int wn = (wave & 1) * 64;
  const unsigned short* gA = Inter + (long)(bm * 128) * FFN;

  f32x4 acc[4][4] = {};
  const int fr = lane & 15;
  const int kg = (lane >> 4) * 8;
  const int p = lane & 15;
  const int h0 = wave * 32 + (lane >> 4) * 8;
  const float* gB = W2 + bn * 128 + h0;

  for (int kt = 0; kt < FFN; kt += 32) {
    __syncthreads();
    stage_tile_128(gA + kt, FFN, As, wave, lane);
    const float* r0p = gB + (long)(kt + 2 * p) * HIDDEN;
    const float* r1p = r0p + HIDDEN;
    const float4 a0 = *reinterpret_cast<const float4*>(r0p);
    const float4 a1 = *reinterpret_cast<const float4*>(r0p + 4);
    const float4 b0 = *reinterpret_cast<const float4*>(r1p);
    const float4 b1 = *reinterpret_cast<const float4*>(r1p + 4);
    unsigned short lo[8], hi[8];
    lo[0] = f2b(a0.x); lo[1] = f2b(a0.y); lo[2] = f2b(a0.z); lo[3] = f2b(a0.w);
    lo[4] = f2b(a1.x); lo[5] = f2b(a1.y); lo[6] = f2b(a1.z); lo[7] = f2b(a1.w);
    hi[0] = f2b(b0.x); hi[1] = f2b(b0.y); hi[2] = f2b(b0.z); hi[3] = f2b(b0.w);
    hi[4] = f2b(b1.x); hi[5] = f2b(b1.y); hi[6] = f2b(b1.z); hi[7] = f2b(b1.w);
#pragma unroll
    for (int j = 0; j < 8; ++j) {
      const unsigned int pack = (unsigned int)lo[j] | ((unsigned int)hi[j] << 16);
      *reinterpret_cast<unsigned int*>(&Bs[(h0 + j) * 32 + 2 * p]) = pack;
    }
    __syncthreads();
    bf16x8 a[4], b[4];
#pragma unroll
    for (int m = 0; m < 4; ++m)
      a[m] = *reinterpret_cast<const bf16x8*>(&As[(wm + m * 16 + fr) * 32 + kg]);
#pragma unroll
    for (int n = 0; n < 4; ++n)
      b[n] = *reinterpret_cast<const bf16x8*>(&Bs[(wn + n * 16 + fr) * 32 + kg]);
#pragma unroll
    for (int m = 0; m < 4; ++m)
#pragma unroll
      for (int n = 0; n < 4; ++n)
        acc[m][n] = MFMA16(a[m], b[n], acc[m][n]);
  }
  const int r0 = (lane >> 4) * 4;
#pragma unroll
  for (int m = 0; m < 4; ++m)
#pragma unroll
    for (int n = 0; n < 4; ++n)
#pragma unroll
      for (int r = 0; r < 4; ++r) {
        const int row = bm * 128 + wm + m * 16 + r0 + r;
        const int col = bn * 128 + wn + n * 16 + fr;
        Out[(long)row * HIDDEN + col] = acc[m][n][r];
      }
}

extern "C" void kernel_launch(void* const* d_in, const int* in_sizes, int n_in,
                              void* d_out, int out_size, void* d_ws, size_t ws_size,
                              hipStream_t stream) {
  const float* x  = (const float*)d_in[0];
  const float* w1 = (const float*)d_in[1];
  const float* v1 = (const float*)d_in[2];
  const float* w2 = (const float*)d_in[3];
  float* out = (float*)d_out;

  // ws layout (bytes): xb 33,554,432 | w1b 117,440,512 | v1b 117,440,512 |
  //                    inter 117,440,512 | w2t 117,440,512  -> 503,316,480 total.
  const size_t REQ_SMALL = 385875968UL;
  const size_t REQ_FULL  = 503316480UL;
  if (ws_size < REQ_SMALL) return;
  const bool full = (ws_size >= REQ_FULL);
  char* ws = (char*)d_ws;
  unsigned short* xb     = (unsigned short*)(ws);
  unsigned short* w1b    = (unsigned short*)(ws + 33554432L);
  unsigned short* v1b    = (unsigned short*)(ws + 150994944L);
  unsigned short* interb = (unsigned short*)(ws + 268435456L);
  unsigned short* w2tb   = (unsigned short*)(ws + 385875968L);

  // half-split: F-rows [0, 8192) = j 0..3 ; F-rows [8192, 14336) = j 4..6
  const long HALF1 = 8192L * HIDDEN;
  const long HALF2 = (long)(FFN - 8192) * HIDDEN;

  hipLaunchKernelGGL(cvt_kernel, dim3(2048), dim3(256), 0, stream, x, xb, (long)TOKENS * HIDDEN);
  hipLaunchKernelGGL(cvt_kernel, dim3(2048), dim3(256), 0, stream, w1, w1b, HALF1);
  hipLaunchKernelGGL(cvt_kernel, dim3(2048), dim3(256), 0, stream, v1, v1b, HALF1);
  hipLaunchKernelGGL(gateup256p_kernel, dim3(256), dim3(512), 0, stream,
                     xb, w1b, v1b, interb, 0, 4);
  hipLaunchKernelGGL(cvt_kernel, dim3(2048), dim3(256), 0, stream, w1 + HALF1, w1b + HALF1, HALF2);
  hipLaunchKernelGGL(cvt_kernel, dim3(2048), dim3(256), 0, stream, v1 + HALF1, v1b + HALF1, HALF2);
  hipLaunchKernelGGL(gateup256p_kernel, dim3(256), dim3(512), 0, stream,
                     xb, w1b, v1b, interb, 4, 7);

  if (full) {
    hipLaunchKernelGGL(transpose_cvt_kernel, dim3(FFN / 64, HIDDEN / 64), dim3(256), 0, stream, w2, w2tb);
    hipLaunchKernelGGL(down256_kernel, dim3((TOKENS / 256) * (HIDDEN / 256)), dim3(512), 0, stream,
                       interb, w2tb, out);
  } else {
    hipLaunchKernelGGL(down_nt_kernel, dim3((TOKENS / 128) * (HIDDEN / 128)), dim3(256), 0, stream,
                       interb, w2, out);
  }
}